// Round 5
// baseline (614.771 us; speedup 1.0000x reference)
//
#include <hip/hip_runtime.h>

typedef unsigned short u16;
typedef __attribute__((ext_vector_type(8))) short bf16x8;
typedef __attribute__((ext_vector_type(4))) short s16x4;
typedef __attribute__((ext_vector_type(4))) float f32x4;

#define GLDS(g, l) __builtin_amdgcn_global_load_lds( \
    (const __attribute__((address_space(1))) unsigned int*)(g), \
    (__attribute__((address_space(3))) unsigned int*)(l), 16, 0, 0)

__device__ __forceinline__ u16 f2b(float f) {
  unsigned int x = __float_as_uint(f);
  return (u16)((x + 0x7fffu + ((x >> 16) & 1u)) >> 16);
}
__device__ __forceinline__ bf16x8 cvt8(float4 a, float4 b) {
  bf16x8 r;
  r[0] = (short)f2b(a.x); r[1] = (short)f2b(a.y);
  r[2] = (short)f2b(a.z); r[3] = (short)f2b(a.w);
  r[4] = (short)f2b(b.x); r[5] = (short)f2b(b.y);
  r[6] = (short)f2b(b.z); r[7] = (short)f2b(b.w);
  return r;
}

// ------------- 1024x1024 weight transpose + f32->bf16: Wt[n][k] = W[k][n] -------------
__global__ __launch_bounds__(256) void transpose_w(const float* __restrict__ W,
                                                   u16* __restrict__ Wt) {
  __shared__ u16 tile[32][33];
  const int tx = threadIdx.x & 31, ty = threadIdx.x >> 5;
  const int r0 = blockIdx.y * 32, c0 = blockIdx.x * 32;
#pragma unroll
  for (int i = 0; i < 32; i += 8)
    tile[ty + i][tx] = f2b(W[(r0 + ty + i) * 1024 + c0 + tx]);
  __syncthreads();
#pragma unroll
  for (int i = 0; i < 32; i += 8)
    Wt[(c0 + ty + i) * 1024 + r0 + tx] = tile[tx][ty + i];
}

// ---------------- C = A(8192x1024) * Bt(1024x1024)^T ----------------
// A: f32 (reg-staged + converted to bf16 in LDS) or bf16 (global_load_lds).
// B: bf16 via global_load_lds width 16. 128x128 tile, BK=32, 4 waves, 16x16x32 MFMA.
// EPI==0: C row-major (B*N, C), element type OT (u16 -> bf16 store, float -> f32 store).
// EPI==1: write V^T per head: Vt[(b,h),dd,n] (OT must be u16).
template <int EPI, typename AT, typename OT>
__global__ __launch_bounds__(256) void gemm_bt(const AT* __restrict__ A,
                                               const u16* __restrict__ Bt,
                                               OT* __restrict__ C) {
  __shared__ u16 As[128 * 32];
  __shared__ u16 Bs[128 * 32];
  const int t = threadIdx.x;
  const int wave = t >> 6, lane = t & 63;
  const int g = lane >> 4, a15 = lane & 15;
  const int wr = wave >> 1, wc = wave & 1;
  const int row0 = t >> 2;            // 0..63
  const int col0 = (t & 3) * 8;       // 0,8,16,24
  const int abase = (blockIdx.x * 128 + row0) * 1024 + col0;
  const int bbase = (blockIdx.y * 128 + row0) * 1024 + col0;
  u16* asl0 = As + wave * 512;        // wave-uniform LDS bases
  u16* asl1 = As + 2048 + wave * 512;
  u16* bsl0 = Bs + wave * 512;
  u16* bsl1 = Bs + 2048 + wave * 512;

  f32x4 acc[4][4] = {};
  for (int kt = 0; kt < 1024; kt += 32) {
    if constexpr (sizeof(AT) == 4) {
      const float* Ag = (const float*)A + abase + kt;
      const float4 x0 = *(const float4*)(Ag);
      const float4 x1 = *(const float4*)(Ag + 4);
      const float4 y0 = *(const float4*)(Ag + 64 * 1024);
      const float4 y1 = *(const float4*)(Ag + 64 * 1024 + 4);
      GLDS(Bt + bbase + kt, bsl0);
      GLDS(Bt + bbase + 64 * 1024 + kt, bsl1);
      *(bf16x8*)&As[row0 * 32 + col0] = cvt8(x0, x1);
      *(bf16x8*)&As[(row0 + 64) * 32 + col0] = cvt8(y0, y1);
    } else {
      GLDS((const u16*)A + abase + kt, asl0);
      GLDS((const u16*)A + abase + 64 * 1024 + kt, asl1);
      GLDS(Bt + bbase + kt, bsl0);
      GLDS(Bt + bbase + 64 * 1024 + kt, bsl1);
    }
    __syncthreads();
    bf16x8 af[4], bfr[4];
#pragma unroll
    for (int mi = 0; mi < 4; ++mi)
      af[mi] = *(const bf16x8*)&As[(wr * 64 + mi * 16 + a15) * 32 + g * 8];
#pragma unroll
    for (int ni = 0; ni < 4; ++ni)
      bfr[ni] = *(const bf16x8*)&Bs[(wc * 64 + ni * 16 + a15) * 32 + g * 8];
#pragma unroll
    for (int mi = 0; mi < 4; ++mi)
#pragma unroll
      for (int ni = 0; ni < 4; ++ni)
        acc[mi][ni] = __builtin_amdgcn_mfma_f32_16x16x32_bf16(af[mi], bfr[ni], acc[mi][ni], 0, 0, 0);
    __syncthreads();
  }
  const int crow = blockIdx.x * 128 + wr * 64 + g * 4;
  const int ccol = blockIdx.y * 128 + wc * 64 + a15;
  if constexpr (EPI == 0) {
#pragma unroll
    for (int mi = 0; mi < 4; ++mi)
#pragma unroll
      for (int ni = 0; ni < 4; ++ni)
#pragma unroll
        for (int r = 0; r < 4; ++r) {
          const float v = acc[mi][ni][r];
          if constexpr (sizeof(OT) == 2)
            C[(crow + mi * 16 + r) * 1024 + ccol + ni * 16] = (OT)f2b(v);
          else
            C[(crow + mi * 16 + r) * 1024 + ccol + ni * 16] = (OT)v;
        }
  } else {
    // Vt[((b*16+h)*64 + dd)*2048 + n], n = crow+mi*16+r, c = ccol+ni*16
#pragma unroll
    for (int mi = 0; mi < 4; ++mi) {
      const int n = crow + mi * 16;
      const int bq = n >> 11;       // batch (tile never crosses the 2048 boundary)
      const int nl = n & 2047;      // multiple of 4 -> 8B aligned stores
#pragma unroll
      for (int ni = 0; ni < 4; ++ni) {
        const int c = ccol + ni * 16;
        s16x4 v4;
        v4[0] = (short)f2b(acc[mi][ni][0]);
        v4[1] = (short)f2b(acc[mi][ni][1]);
        v4[2] = (short)f2b(acc[mi][ni][2]);
        v4[3] = (short)f2b(acc[mi][ni][3]);
        *(s16x4*)&((u16*)C)[(((bq << 4) + (c >> 6)) * 64 + (c & 63)) * 2048 + nl] = v4;
      }
    }
  }
}

// ---------------- flash attention with policy-masked softmax ----------------
// grid (32 qblocks, 64 bh). 4 waves/block, 16 q-rows per wave, KV step = 64.
// Swapped QK^T: S^T = K*Q^T so P[qrow=lane&15][key=sub*16+4g+r] per lane.
// O aliases Q: each block reads only its own 64-row x 64-col region at start
// and overwrites exactly that region at the end (regions disjoint per block).
__global__ __launch_bounds__(256) void attn_kernel(
    const u16* Q, const u16* __restrict__ K,
    const u16* __restrict__ Vt, const float* __restrict__ dec,
    u16* O) {
  const int bh = blockIdx.y, b = bh >> 4, h = bh & 15;
  __shared__ float p_lds[2048];
  __shared__ u16 P_lds[4][16 * 72];  // per-wave 16 rows x 64 keys, stride 72
  {
    const int i0 = threadIdx.x * 8;
    const float4 d0 = *(const float4*)&dec[b * 2048 + i0];
    const float4 d1 = *(const float4*)&dec[b * 2048 + i0 + 4];
    p_lds[i0 + 0] = 1.0f - d0.x; p_lds[i0 + 1] = 1.0f - d0.y;
    p_lds[i0 + 2] = 1.0f - d0.z; p_lds[i0 + 3] = 1.0f - d0.w;
    p_lds[i0 + 4] = 1.0f - d1.x; p_lds[i0 + 5] = 1.0f - d1.y;
    p_lds[i0 + 6] = 1.0f - d1.z; p_lds[i0 + 7] = 1.0f - d1.w;
  }
  __syncthreads();

  const int wave = threadIdx.x >> 6, lane = threadIdx.x & 63;
  const int g = lane >> 4, a15 = lane & 15;
  u16* pl = &P_lds[wave][0];

  const int qrow = blockIdx.x * 64 + wave * 16 + a15;
  const int qoff = (b * 2048 + qrow) * 1024 + h * 64 + g * 8;
  const bf16x8 qf0 = *(const bf16x8*)&Q[qoff];
  const bf16x8 qf1 = *(const bf16x8*)&Q[qoff + 32];

  const u16* Kb = K + b * 2048 * 1024 + h * 64 + g * 8;          // + key*1024
  const u16* Vb = Vt + bh * 64 * 2048 + a15 * 2048 + g * 8;      // + ni*16*2048 + key

  f32x4 acc[4] = {};
  float m = -1e30f, lsum = 0.f;

  for (int kt = 0; kt < 2048; kt += 64) {
    // --- S^T = K * Q^T (keys x qrows), 16 keys per sub ---
    f32x4 sf[4];
#pragma unroll
    for (int sub = 0; sub < 4; ++sub) {
      const u16* kp = Kb + (kt + sub * 16 + a15) * 1024;
      const bf16x8 k0 = *(const bf16x8*)kp;
      const bf16x8 k1 = *(const bf16x8*)(kp + 32);
      f32x4 s = {0.f, 0.f, 0.f, 0.f};
      s = __builtin_amdgcn_mfma_f32_16x16x32_bf16(k0, qf0, s, 0, 0, 0);
      s = __builtin_amdgcn_mfma_f32_16x16x32_bf16(k1, qf1, s, 0, 0, 0);
      sf[sub] = s;
    }
    // --- online softmax over this 64-key tile ---
    float mt = -1e30f;
#pragma unroll
    for (int sub = 0; sub < 4; ++sub)
#pragma unroll
      for (int r = 0; r < 4; ++r) {
        const float v = sf[sub][r] * 0.125f;
        sf[sub][r] = v;
        mt = fmaxf(mt, v);
      }
    mt = fmaxf(mt, __shfl_xor(mt, 16));
    mt = fmaxf(mt, __shfl_xor(mt, 32));
    const float mnew = fmaxf(m, mt);
    const float fs = __expf(m - mnew);
    m = mnew;
    float lt = 0.f;
#pragma unroll
    for (int sub = 0; sub < 4; ++sub) {
      const float4 pv = *(const float4*)&p_lds[kt + sub * 16 + g * 4];
      const float e0 = __expf(sf[sub][0] - mnew) * pv.x;
      const float e1 = __expf(sf[sub][1] - mnew) * pv.y;
      const float e2 = __expf(sf[sub][2] - mnew) * pv.z;
      const float e3 = __expf(sf[sub][3] - mnew) * pv.w;
      lt += (e0 + e1) + (e2 + e3);
      s16x4 pb;
      pb[0] = (short)f2b(e0); pb[1] = (short)f2b(e1);
      pb[2] = (short)f2b(e2); pb[3] = (short)f2b(e3);
      *(s16x4*)&pl[a15 * 72 + sub * 16 + g * 4] = pb;
    }
    lt += __shfl_xor(lt, 16);
    lt += __shfl_xor(lt, 32);
    lsum = lsum * fs + lt;
    // rescale accumulator (acc rows live at qrow = g*4+r -> gather fs)
    const float fs0 = __shfl(fs, g * 4 + 0);
    const float fs1 = __shfl(fs, g * 4 + 1);
    const float fs2 = __shfl(fs, g * 4 + 2);
    const float fs3 = __shfl(fs, g * 4 + 3);
#pragma unroll
    for (int ni = 0; ni < 4; ++ni) {
      acc[ni][0] *= fs0; acc[ni][1] *= fs1;
      acc[ni][2] *= fs2; acc[ni][3] *= fs3;
    }
    asm volatile("" ::: "memory");  // order P_lds writes before PV reads
    // --- PV: out += P(16xkeys) * V(keys x 64dd) ---
#pragma unroll
    for (int kc = 0; kc < 2; ++kc) {
      const bf16x8 pa = *(const bf16x8*)&pl[a15 * 72 + kc * 32 + g * 8];
#pragma unroll
      for (int ni = 0; ni < 4; ++ni) {
        const bf16x8 vb = *(const bf16x8*)&Vb[ni * 16 * 2048 + kt + kc * 32];
        acc[ni] = __builtin_amdgcn_mfma_f32_16x16x32_bf16(pa, vb, acc[ni], 0, 0, 0);
      }
    }
    asm volatile("" ::: "memory");  // order PV reads before next-iter P writes
  }
  const float li0 = 1.f / (__shfl(lsum, g * 4 + 0) + 1e-6f);
  const float li1 = 1.f / (__shfl(lsum, g * 4 + 1) + 1e-6f);
  const float li2 = 1.f / (__shfl(lsum, g * 4 + 2) + 1e-6f);
  const float li3 = 1.f / (__shfl(lsum, g * 4 + 3) + 1e-6f);
  const int obase = (b * 2048 + blockIdx.x * 64 + wave * 16 + g * 4) * 1024 + h * 64 + a15;
#pragma unroll
  for (int ni = 0; ni < 4; ++ni) {
    O[obase + 0 * 1024 + ni * 16] = f2b(acc[ni][0] * li0);
    O[obase + 1 * 1024 + ni * 16] = f2b(acc[ni][1] * li1);
    O[obase + 2 * 1024 + ni * 16] = f2b(acc[ni][2] * li2);
    O[obase + 3 * 1024 + ni * 16] = f2b(acc[ni][3] * li3);
  }
}

extern "C" void kernel_launch(void* const* d_in, const int* in_sizes, int n_in,
                              void* d_out, int out_size, void* d_ws, size_t ws_size,
                              hipStream_t stream) {
  (void)in_sizes; (void)n_in; (void)out_size; (void)ws_size;
  const float* x   = (const float*)d_in[0];
  const float* xo  = (const float*)d_in[1];
  const float* dec = (const float*)d_in[2];
  const float* Wq  = (const float*)d_in[3];
  const float* Wk  = (const float*)d_in[4];
  const float* Wv  = (const float*)d_in[5];
  const float* Wp  = (const float*)d_in[6];
  float* out = (float*)d_out;   // reference output dtype is float32

  // ws layout (50 MB total):
  //   Wt  @  0MB (2MB)   reused for all four transposed bf16 weights
  //   Qb  @  2MB (16MB)  Q bf16, later overwritten in-place by attention out
  //   Kb  @ 18MB (16MB)  K bf16
  //   Vtb @ 34MB (16MB)  V^T bf16 (B,H,d,N), written directly by gemm epilogue
  char* ws = (char*)d_ws;
  u16* Wt  = (u16*)(ws + ((size_t)0 << 20));
  u16* Qb  = (u16*)(ws + ((size_t)2 << 20));
  u16* Kb  = (u16*)(ws + ((size_t)18 << 20));
  u16* Vtb = (u16*)(ws + ((size_t)34 << 20));

  const dim3 blk(256);
  transpose_w<<<dim3(32, 32), blk, 0, stream>>>(Wq, Wt);
  gemm_bt<0, float, u16><<<dim3(64, 8), blk, 0, stream>>>(x, Wt, Qb);

  transpose_w<<<dim3(32, 32), blk, 0, stream>>>(Wk, Wt);
  gemm_bt<0, float, u16><<<dim3(64, 8), blk, 0, stream>>>(xo, Wt, Kb);

  transpose_w<<<dim3(32, 32), blk, 0, stream>>>(Wv, Wt);
  gemm_bt<1, float, u16><<<dim3(64, 8), blk, 0, stream>>>(xo, Wt, Vtb);

  transpose_w<<<dim3(32, 32), blk, 0, stream>>>(Wp, Wt);

  attn_kernel<<<dim3(32, 64), blk, 0, stream>>>(Qb, Kb, Vtb, dec, Qb);

  gemm_bt<0, u16, float><<<dim3(64, 8), blk, 0, stream>>>(Qb, Wt, out);
}

// Round 6
// 314.253 us; speedup vs baseline: 1.9563x; 1.9563x over previous
//
#include <hip/hip_runtime.h>

typedef unsigned short u16;
typedef __attribute__((ext_vector_type(8))) short bf16x8;
typedef __attribute__((ext_vector_type(4))) short s16x4;
typedef __attribute__((ext_vector_type(4))) float f32x4;

#define GLDS(g, l) __builtin_amdgcn_global_load_lds( \
    (const __attribute__((address_space(1))) unsigned int*)(g), \
    (__attribute__((address_space(3))) unsigned int*)(l), 16, 0, 0)

__device__ __forceinline__ u16 f2b(float f) {
  unsigned int x = __float_as_uint(f);
  return (u16)((x + 0x7fffu + ((x >> 16) & 1u)) >> 16);
}
__device__ __forceinline__ bf16x8 cvt8(float4 a, float4 b) {
  bf16x8 r;
  r[0] = (short)f2b(a.x); r[1] = (short)f2b(a.y);
  r[2] = (short)f2b(a.z); r[3] = (short)f2b(a.w);
  r[4] = (short)f2b(b.x); r[5] = (short)f2b(b.y);
  r[6] = (short)f2b(b.z); r[7] = (short)f2b(b.w);
  return r;
}

// ------------- 1024x1024 weight transpose + f32->bf16: Wt[n][k] = W[k][n] -------------
__global__ __launch_bounds__(256) void transpose_w(const float* __restrict__ W,
                                                   u16* __restrict__ Wt) {
  __shared__ u16 tile[32][33];
  const int tx = threadIdx.x & 31, ty = threadIdx.x >> 5;
  const int r0 = blockIdx.y * 32, c0 = blockIdx.x * 32;
#pragma unroll
  for (int i = 0; i < 32; i += 8)
    tile[ty + i][tx] = f2b(W[(r0 + ty + i) * 1024 + c0 + tx]);
  __syncthreads();
#pragma unroll
  for (int i = 0; i < 32; i += 8)
    Wt[(c0 + ty + i) * 1024 + r0 + tx] = tile[tx][ty + i];
}

// ---------------- C = A(8192x1024) * Bt(1024x1024)^T ----------------
// A: f32 (reg-staged + converted to bf16 in LDS) or bf16 (global_load_lds).
// B: bf16 via global_load_lds width 16. 128x128 tile, BK=32, 4 waves, 16x16x32 MFMA.
// EPI==0: C row-major (B*N, C), element type OT (u16 -> bf16 store, float -> f32 store).
// EPI==1: write V^T per head: Vt[(b,h),dd,n] (OT must be u16).
template <int EPI, typename AT, typename OT>
__global__ __launch_bounds__(256) void gemm_bt(const AT* __restrict__ A,
                                               const u16* __restrict__ Bt,
                                               OT* __restrict__ C) {
  __shared__ u16 As[128 * 32];
  __shared__ u16 Bs[128 * 32];
  const int t = threadIdx.x;
  const int wave = t >> 6, lane = t & 63;
  const int g = lane >> 4, a15 = lane & 15;
  const int wr = wave >> 1, wc = wave & 1;
  const int row0 = t >> 2;            // 0..63
  const int col0 = (t & 3) * 8;       // 0,8,16,24
  const int abase = (blockIdx.x * 128 + row0) * 1024 + col0;
  const int bbase = (blockIdx.y * 128 + row0) * 1024 + col0;
  u16* asl0 = As + wave * 512;        // wave-uniform LDS bases
  u16* asl1 = As + 2048 + wave * 512;
  u16* bsl0 = Bs + wave * 512;
  u16* bsl1 = Bs + 2048 + wave * 512;

  f32x4 acc[4][4] = {};
  for (int kt = 0; kt < 1024; kt += 32) {
    if constexpr (sizeof(AT) == 4) {
      const float* Ag = (const float*)A + abase + kt;
      const float4 x0 = *(const float4*)(Ag);
      const float4 x1 = *(const float4*)(Ag + 4);
      const float4 y0 = *(const float4*)(Ag + 64 * 1024);
      const float4 y1 = *(const float4*)(Ag + 64 * 1024 + 4);
      GLDS(Bt + bbase + kt, bsl0);
      GLDS(Bt + bbase + 64 * 1024 + kt, bsl1);
      *(bf16x8*)&As[row0 * 32 + col0] = cvt8(x0, x1);
      *(bf16x8*)&As[(row0 + 64) * 32 + col0] = cvt8(y0, y1);
    } else {
      GLDS((const u16*)A + abase + kt, asl0);
      GLDS((const u16*)A + abase + 64 * 1024 + kt, asl1);
      GLDS(Bt + bbase + kt, bsl0);
      GLDS(Bt + bbase + 64 * 1024 + kt, bsl1);
    }
    __syncthreads();
    bf16x8 af[4], bfr[4];
#pragma unroll
    for (int mi = 0; mi < 4; ++mi)
      af[mi] = *(const bf16x8*)&As[(wr * 64 + mi * 16 + a15) * 32 + g * 8];
#pragma unroll
    for (int ni = 0; ni < 4; ++ni)
      bfr[ni] = *(const bf16x8*)&Bs[(wc * 64 + ni * 16 + a15) * 32 + g * 8];
#pragma unroll
    for (int mi = 0; mi < 4; ++mi)
#pragma unroll
      for (int ni = 0; ni < 4; ++ni)
        acc[mi][ni] = __builtin_amdgcn_mfma_f32_16x16x32_bf16(af[mi], bfr[ni], acc[mi][ni], 0, 0, 0);
    __syncthreads();
  }
  const int crow = blockIdx.x * 128 + wr * 64 + g * 4;
  const int ccol = blockIdx.y * 128 + wc * 64 + a15;
  if constexpr (EPI == 0) {
#pragma unroll
    for (int mi = 0; mi < 4; ++mi)
#pragma unroll
      for (int ni = 0; ni < 4; ++ni)
#pragma unroll
        for (int r = 0; r < 4; ++r) {
          const float v = acc[mi][ni][r];
          if constexpr (sizeof(OT) == 2)
            C[(crow + mi * 16 + r) * 1024 + ccol + ni * 16] = (OT)f2b(v);
          else
            C[(crow + mi * 16 + r) * 1024 + ccol + ni * 16] = (OT)v;
        }
  } else {
    // Vt[((b*16+h)*64 + dd)*2048 + n], n = crow+mi*16+r, c = ccol+ni*16
#pragma unroll
    for (int mi = 0; mi < 4; ++mi) {
      const int n = crow + mi * 16;
      const int bq = n >> 11;       // batch (tile never crosses the 2048 boundary)
      const int nl = n & 2047;      // multiple of 4 -> 8B aligned stores
#pragma unroll
      for (int ni = 0; ni < 4; ++ni) {
        const int c = ccol + ni * 16;
        s16x4 v4;
        v4[0] = (short)f2b(acc[mi][ni][0]);
        v4[1] = (short)f2b(acc[mi][ni][1]);
        v4[2] = (short)f2b(acc[mi][ni][2]);
        v4[3] = (short)f2b(acc[mi][ni][3]);
        *(s16x4*)&((u16*)C)[(((bq << 4) + (c >> 6)) * 64 + (c & 63)) * 2048 + nl] = v4;
      }
    }
  }
}

// ---------------- flash attention with policy-masked softmax ----------------
// grid (32 qblocks, 64 bh). 4 waves/block, 16 q-rows per wave, KV step = 64.
// K/V tiles staged in LDS via global_load_lds (width 16), XOR-swizzled rows
// (rule-21: linear LDS dest + inverse-swizzled GLOBAL src + swizzled ds_read).
// Swapped QK^T: S^T = K*Q^T so P[qrow=lane&15][key=sub*16+4g+r] per lane.
// O aliases Q: each block reads only its own 64-row x 64-col region at start
// and overwrites exactly that region at the end (regions disjoint per block).
__global__ __launch_bounds__(256) void attn_kernel(
    const u16* Q, const u16* __restrict__ K,
    const u16* __restrict__ Vt, const float* __restrict__ dec,
    u16* O) {
  const int bh = blockIdx.y, b = bh >> 4, h = bh & 15;
  __shared__ float p_lds[2048];
  __shared__ u16 K_lds[64 * 64];     // [key][dim], rows XOR-swizzled (8KB)
  __shared__ u16 V_lds[64 * 64];     // [dd][key], rows XOR-swizzled (8KB)
  __shared__ u16 P_lds[4][16 * 72];  // per-wave 16 rows x 64 keys, stride 72
  {
    const int i0 = threadIdx.x * 8;
    const float4 d0 = *(const float4*)&dec[b * 2048 + i0];
    const float4 d1 = *(const float4*)&dec[b * 2048 + i0 + 4];
    p_lds[i0 + 0] = 1.0f - d0.x; p_lds[i0 + 1] = 1.0f - d0.y;
    p_lds[i0 + 2] = 1.0f - d0.z; p_lds[i0 + 3] = 1.0f - d0.w;
    p_lds[i0 + 4] = 1.0f - d1.x; p_lds[i0 + 5] = 1.0f - d1.y;
    p_lds[i0 + 6] = 1.0f - d1.z; p_lds[i0 + 7] = 1.0f - d1.w;
  }

  const int wave = threadIdx.x >> 6, lane = threadIdx.x & 63;
  const int g = lane >> 4, a15 = lane & 15;
  u16* pl = &P_lds[wave][0];

  const int qrow = blockIdx.x * 64 + wave * 16 + a15;
  const int qoff = (b * 2048 + qrow) * 1024 + h * 64 + g * 8;
  const bf16x8 qf0 = *(const bf16x8*)&Q[qoff];
  const bf16x8 qf1 = *(const bf16x8*)&Q[qoff + 32];

  // --- staging lane mapping: row-in-8 = lane>>3, colByte = (lane&7)*16.
  // Tile rows step by 8 per GLDS, so (tile_row & 7) == (lane>>3) always:
  // the XOR swizzle on the global source column is a per-lane constant.
  const int srow = lane >> 3;
  const int swze = (((lane & 7) * 16) ^ (srow << 4)) >> 1;  // u16 elems
  // K global: + (kt + rloc)*1024 per row;  V^T global: row=dd, + kt per tile
  const u16* Kg = K + ((size_t)(b * 2048 + wave * 16 + srow)) * 1024 + h * 64 + swze;
  const u16* Vg = Vt + ((size_t)(bh * 64 + wave * 16 + srow)) * 2048 + swze;
  u16* kdst0 = &K_lds[(wave * 16 + 0) * 64];
  u16* kdst1 = &K_lds[(wave * 16 + 8) * 64];
  u16* vdst0 = &V_lds[(wave * 16 + 0) * 64];
  u16* vdst1 = &V_lds[(wave * 16 + 8) * 64];

  f32x4 acc[4] = {};
  float m = -1e30f, lsum = 0.f;

  for (int kt = 0; kt < 2048; kt += 64) {
    // --- stage K,V tiles (each wave stages its own 16 rows of each) ---
    GLDS(Kg + (size_t)kt * 1024, kdst0);
    GLDS(Kg + (size_t)(kt + 8) * 1024, kdst1);
    GLDS(Vg + kt, vdst0);
    GLDS(Vg + kt + 8 * 2048, vdst1);
    __syncthreads();

    // --- S^T = K * Q^T (keys x qrows), 16 keys per sub ---
    f32x4 sf[4];
#pragma unroll
    for (int sub = 0; sub < 4; ++sub) {
      const int krow = sub * 16 + a15;
      const char* kp = (const char*)&K_lds[krow * 64];
      const int swz = (krow & 7) << 4;
      const bf16x8 k0 = *(const bf16x8*)(kp + ((g * 16) ^ swz));
      const bf16x8 k1 = *(const bf16x8*)(kp + ((g * 16 + 64) ^ swz));
      f32x4 s = {0.f, 0.f, 0.f, 0.f};
      s = __builtin_amdgcn_mfma_f32_16x16x32_bf16(k0, qf0, s, 0, 0, 0);
      s = __builtin_amdgcn_mfma_f32_16x16x32_bf16(k1, qf1, s, 0, 0, 0);
      sf[sub] = s;
    }
    // --- online softmax over this 64-key tile ---
    float mt = -1e30f;
#pragma unroll
    for (int sub = 0; sub < 4; ++sub)
#pragma unroll
      for (int r = 0; r < 4; ++r) {
        const float v = sf[sub][r] * 0.125f;
        sf[sub][r] = v;
        mt = fmaxf(mt, v);
      }
    mt = fmaxf(mt, __shfl_xor(mt, 16));
    mt = fmaxf(mt, __shfl_xor(mt, 32));
    const float mnew = fmaxf(m, mt);
    const float fs = __expf(m - mnew);
    m = mnew;
    float lt = 0.f;
#pragma unroll
    for (int sub = 0; sub < 4; ++sub) {
      const float4 pv = *(const float4*)&p_lds[kt + sub * 16 + g * 4];
      const float e0 = __expf(sf[sub][0] - mnew) * pv.x;
      const float e1 = __expf(sf[sub][1] - mnew) * pv.y;
      const float e2 = __expf(sf[sub][2] - mnew) * pv.z;
      const float e3 = __expf(sf[sub][3] - mnew) * pv.w;
      lt += (e0 + e1) + (e2 + e3);
      s16x4 pb;
      pb[0] = (short)f2b(e0); pb[1] = (short)f2b(e1);
      pb[2] = (short)f2b(e2); pb[3] = (short)f2b(e3);
      *(s16x4*)&pl[a15 * 72 + sub * 16 + g * 4] = pb;
    }
    lt += __shfl_xor(lt, 16);
    lt += __shfl_xor(lt, 32);
    lsum = lsum * fs + lt;
    // rescale accumulator (acc rows live at qrow = g*4+r -> gather fs)
    const float fs0 = __shfl(fs, g * 4 + 0);
    const float fs1 = __shfl(fs, g * 4 + 1);
    const float fs2 = __shfl(fs, g * 4 + 2);
    const float fs3 = __shfl(fs, g * 4 + 3);
#pragma unroll
    for (int ni = 0; ni < 4; ++ni) {
      acc[ni][0] *= fs0; acc[ni][1] *= fs1;
      acc[ni][2] *= fs2; acc[ni][3] *= fs3;
    }
    asm volatile("" ::: "memory");  // order P_lds writes before PV reads
    // --- PV: out += P(16xkeys) * V(keys x 64dd) ---
#pragma unroll
    for (int kc = 0; kc < 2; ++kc) {
      const bf16x8 pa = *(const bf16x8*)&pl[a15 * 72 + kc * 32 + g * 8];
#pragma unroll
      for (int ni = 0; ni < 4; ++ni) {
        const int vrow = ni * 16 + a15;
        const char* vp = (const char*)&V_lds[vrow * 64];
        const int vswz = (vrow & 7) << 4;
        const bf16x8 vb = *(const bf16x8*)(vp + ((kc * 64 + g * 16) ^ vswz));
        acc[ni] = __builtin_amdgcn_mfma_f32_16x16x32_bf16(pa, vb, acc[ni], 0, 0, 0);
      }
    }
    __syncthreads();  // all LDS reads done before next stage overwrites
  }
  const float li0 = 1.f / (__shfl(lsum, g * 4 + 0) + 1e-6f);
  const float li1 = 1.f / (__shfl(lsum, g * 4 + 1) + 1e-6f);
  const float li2 = 1.f / (__shfl(lsum, g * 4 + 2) + 1e-6f);
  const float li3 = 1.f / (__shfl(lsum, g * 4 + 3) + 1e-6f);
  const int obase = (b * 2048 + blockIdx.x * 64 + wave * 16 + g * 4) * 1024 + h * 64 + a15;
#pragma unroll
  for (int ni = 0; ni < 4; ++ni) {
    O[obase + 0 * 1024 + ni * 16] = f2b(acc[ni][0] * li0);
    O[obase + 1 * 1024 + ni * 16] = f2b(acc[ni][1] * li1);
    O[obase + 2 * 1024 + ni * 16] = f2b(acc[ni][2] * li2);
    O[obase + 3 * 1024 + ni * 16] = f2b(acc[ni][3] * li3);
  }
}

extern "C" void kernel_launch(void* const* d_in, const int* in_sizes, int n_in,
                              void* d_out, int out_size, void* d_ws, size_t ws_size,
                              hipStream_t stream) {
  (void)in_sizes; (void)n_in; (void)out_size; (void)ws_size;
  const float* x   = (const float*)d_in[0];
  const float* xo  = (const float*)d_in[1];
  const float* dec = (const float*)d_in[2];
  const float* Wq  = (const float*)d_in[3];
  const float* Wk  = (const float*)d_in[4];
  const float* Wv  = (const float*)d_in[5];
  const float* Wp  = (const float*)d_in[6];
  float* out = (float*)d_out;   // reference output dtype is float32

  // ws layout (50 MB total):
  //   Wt  @  0MB (2MB)   reused for all four transposed bf16 weights
  //   Qb  @  2MB (16MB)  Q bf16, later overwritten in-place by attention out
  //   Kb  @ 18MB (16MB)  K bf16
  //   Vtb @ 34MB (16MB)  V^T bf16 (B,H,d,N), written directly by gemm epilogue
  char* ws = (char*)d_ws;
  u16* Wt  = (u16*)(ws + ((size_t)0 << 20));
  u16* Qb  = (u16*)(ws + ((size_t)2 << 20));
  u16* Kb  = (u16*)(ws + ((size_t)18 << 20));
  u16* Vtb = (u16*)(ws + ((size_t)34 << 20));

  const dim3 blk(256);
  transpose_w<<<dim3(32, 32), blk, 0, stream>>>(Wq, Wt);
  gemm_bt<0, float, u16><<<dim3(64, 8), blk, 0, stream>>>(x, Wt, Qb);

  transpose_w<<<dim3(32, 32), blk, 0, stream>>>(Wk, Wt);
  gemm_bt<0, float, u16><<<dim3(64, 8), blk, 0, stream>>>(xo, Wt, Kb);

  transpose_w<<<dim3(32, 32), blk, 0, stream>>>(Wv, Wt);
  gemm_bt<1, float, u16><<<dim3(64, 8), blk, 0, stream>>>(xo, Wt, Vtb);

  transpose_w<<<dim3(32, 32), blk, 0, stream>>>(Wp, Wt);

  attn_kernel<<<dim3(32, 64), blk, 0, stream>>>(Qb, Kb, Vtb, dec, Qb);

  gemm_bt<0, u16, float><<<dim3(64, 8), blk, 0, stream>>>(Qb, Wt, out);
}

// Round 7
// 292.068 us; speedup vs baseline: 2.1049x; 1.0760x over previous
//
#include <hip/hip_runtime.h>

typedef unsigned short u16;
typedef __attribute__((ext_vector_type(8))) short bf16x8;
typedef __attribute__((ext_vector_type(4))) short s16x4;
typedef __attribute__((ext_vector_type(4))) float f32x4;

#define GLDS(g, l) __builtin_amdgcn_global_load_lds( \
    (const __attribute__((address_space(1))) unsigned int*)(g), \
    (__attribute__((address_space(3))) unsigned int*)(l), 16, 0, 0)

__device__ __forceinline__ u16 f2b(float f) {
  unsigned int x = __float_as_uint(f);
  return (u16)((x + 0x7fffu + ((x >> 16) & 1u)) >> 16);
}
__device__ __forceinline__ bf16x8 cvt8(float4 a, float4 b) {
  bf16x8 r;
  r[0] = (short)f2b(a.x); r[1] = (short)f2b(a.y);
  r[2] = (short)f2b(a.z); r[3] = (short)f2b(a.w);
  r[4] = (short)f2b(b.x); r[5] = (short)f2b(b.y);
  r[6] = (short)f2b(b.z); r[7] = (short)f2b(b.w);
  return r;
}

// ------------- 1024x1024 weight transpose + f32->bf16: Wt[n][k] = W[k][n] -------------
__global__ __launch_bounds__(256) void transpose_w(const float* __restrict__ W,
                                                   u16* __restrict__ Wt) {
  __shared__ u16 tile[32][33];
  const int tx = threadIdx.x & 31, ty = threadIdx.x >> 5;
  const int r0 = blockIdx.y * 32, c0 = blockIdx.x * 32;
#pragma unroll
  for (int i = 0; i < 32; i += 8)
    tile[ty + i][tx] = f2b(W[(r0 + ty + i) * 1024 + c0 + tx]);
  __syncthreads();
#pragma unroll
  for (int i = 0; i < 32; i += 8)
    Wt[(c0 + ty + i) * 1024 + r0 + tx] = tile[tx][ty + i];
}

// ------------- l2p[i] = log2(1 - decisions[i]) (policy folded into scores) -------------
__global__ __launch_bounds__(256) void prep_l2p(const float* __restrict__ dec,
                                                float* __restrict__ l2p) {
  const int i = blockIdx.x * 256 + threadIdx.x;
  const float p = fmaxf(1.0f - dec[i], 1e-38f);
  l2p[i] = __log2f(p);
}

// ---------------- C = A(8192x1024) * Bt(1024x1024)^T ----------------
// A: f32 (reg-staged + converted to bf16 in LDS) or bf16 (global_load_lds).
// B: bf16 via global_load_lds width 16. 128x128 tile, BK=32, 4 waves, 16x16x32 MFMA.
// EPI==0: C row-major (B*N, C), element type OT (u16 -> bf16 store, float -> f32 store).
// EPI==1: write V^T per head: Vt[(b,h),dd,n] (OT must be u16).
template <int EPI, typename AT, typename OT>
__global__ __launch_bounds__(256) void gemm_bt(const AT* __restrict__ A,
                                               const u16* __restrict__ Bt,
                                               OT* __restrict__ C) {
  __shared__ u16 As[128 * 32];
  __shared__ u16 Bs[128 * 32];
  const int t = threadIdx.x;
  const int wave = t >> 6, lane = t & 63;
  const int g = lane >> 4, a15 = lane & 15;
  const int wr = wave >> 1, wc = wave & 1;
  const int row0 = t >> 2;            // 0..63
  const int col0 = (t & 3) * 8;       // 0,8,16,24
  const int abase = (blockIdx.x * 128 + row0) * 1024 + col0;
  const int bbase = (blockIdx.y * 128 + row0) * 1024 + col0;
  u16* asl0 = As + wave * 512;        // wave-uniform LDS bases
  u16* asl1 = As + 2048 + wave * 512;
  u16* bsl0 = Bs + wave * 512;
  u16* bsl1 = Bs + 2048 + wave * 512;

  f32x4 acc[4][4] = {};
  for (int kt = 0; kt < 1024; kt += 32) {
    if constexpr (sizeof(AT) == 4) {
      const float* Ag = (const float*)A + abase + kt;
      const float4 x0 = *(const float4*)(Ag);
      const float4 x1 = *(const float4*)(Ag + 4);
      const float4 y0 = *(const float4*)(Ag + 64 * 1024);
      const float4 y1 = *(const float4*)(Ag + 64 * 1024 + 4);
      GLDS(Bt + bbase + kt, bsl0);
      GLDS(Bt + bbase + 64 * 1024 + kt, bsl1);
      *(bf16x8*)&As[row0 * 32 + col0] = cvt8(x0, x1);
      *(bf16x8*)&As[(row0 + 64) * 32 + col0] = cvt8(y0, y1);
    } else {
      GLDS((const u16*)A + abase + kt, asl0);
      GLDS((const u16*)A + abase + 64 * 1024 + kt, asl1);
      GLDS(Bt + bbase + kt, bsl0);
      GLDS(Bt + bbase + 64 * 1024 + kt, bsl1);
    }
    __syncthreads();
    bf16x8 af[4], bfr[4];
#pragma unroll
    for (int mi = 0; mi < 4; ++mi)
      af[mi] = *(const bf16x8*)&As[(wr * 64 + mi * 16 + a15) * 32 + g * 8];
#pragma unroll
    for (int ni = 0; ni < 4; ++ni)
      bfr[ni] = *(const bf16x8*)&Bs[(wc * 64 + ni * 16 + a15) * 32 + g * 8];
#pragma unroll
    for (int mi = 0; mi < 4; ++mi)
#pragma unroll
      for (int ni = 0; ni < 4; ++ni)
        acc[mi][ni] = __builtin_amdgcn_mfma_f32_16x16x32_bf16(af[mi], bfr[ni], acc[mi][ni], 0, 0, 0);
    __syncthreads();
  }
  const int crow = blockIdx.x * 128 + wr * 64 + g * 4;
  const int ccol = blockIdx.y * 128 + wc * 64 + a15;
  if constexpr (EPI == 0) {
#pragma unroll
    for (int mi = 0; mi < 4; ++mi)
#pragma unroll
      for (int ni = 0; ni < 4; ++ni)
#pragma unroll
        for (int r = 0; r < 4; ++r) {
          const float v = acc[mi][ni][r];
          if constexpr (sizeof(OT) == 2)
            C[(crow + mi * 16 + r) * 1024 + ccol + ni * 16] = (OT)f2b(v);
          else
            C[(crow + mi * 16 + r) * 1024 + ccol + ni * 16] = (OT)v;
        }
  } else {
    // Vt[((b*16+h)*64 + dd)*2048 + n], n = crow+mi*16+r, c = ccol+ni*16
#pragma unroll
    for (int mi = 0; mi < 4; ++mi) {
      const int n = crow + mi * 16;
      const int bq = n >> 11;       // batch (tile never crosses the 2048 boundary)
      const int nl = n & 2047;      // multiple of 4 -> 8B aligned stores
#pragma unroll
      for (int ni = 0; ni < 4; ++ni) {
        const int c = ccol + ni * 16;
        s16x4 v4;
        v4[0] = (short)f2b(acc[mi][ni][0]);
        v4[1] = (short)f2b(acc[mi][ni][1]);
        v4[2] = (short)f2b(acc[mi][ni][2]);
        v4[3] = (short)f2b(acc[mi][ni][3]);
        *(s16x4*)&((u16*)C)[(((bq << 4) + (c >> 6)) * 64 + (c & 63)) * 2048 + nl] = v4;
      }
    }
  }
}

// ---------------- flash attention, policy folded into log2-domain scores ----------------
// 1-D grid 2048, XCD-aware remap: xcd = f&7 owns bh in [xcd*8, xcd*8+8) -> K/V head
// L2-resident per XCD. 4 waves/block, 16 q-rows/wave, KV step 64.
// K/V staged via global_load_lds w16, XOR-swizzled (rule 21: inverse-swz src + swz read).
// Swapped QK^T; defer-max (THR=8); lsum reduced across lanes once at the end.
// O aliases Q (disjoint per-block read/write regions, dep through acc).
__global__ __launch_bounds__(256) void attn_kernel(
    const u16* Q, const u16* __restrict__ K,
    const u16* __restrict__ Vt, const float* __restrict__ l2p,
    u16* O) {
  const int f = blockIdx.x;
  const int bh = (f & 7) * 8 + (f >> 8);     // 8 heads per XCD
  const int qx = (f >> 3) & 31;
  const int b = bh >> 4, h = bh & 15;
  __shared__ u16 K_lds[64 * 64];     // [key][dim], rows XOR-swizzled (8KB)
  __shared__ u16 V_lds[64 * 64];     // [dd][key], rows XOR-swizzled (8KB)
  __shared__ __align__(16) u16 P_lds[4][16 * 72];  // per-wave 16 q x 64 keys

  const int wave = threadIdx.x >> 6, lane = threadIdx.x & 63;
  const int g = lane >> 4, a15 = lane & 15;
  u16* pl = &P_lds[wave][0];

  const int qrow = qx * 64 + wave * 16 + a15;
  const int qoff = (b * 2048 + qrow) * 1024 + h * 64 + g * 8;
  const bf16x8 qf0 = *(const bf16x8*)&Q[qoff];
  const bf16x8 qf1 = *(const bf16x8*)&Q[qoff + 32];

  // staging lane mapping: row-in-8 = lane>>3, colByte = (lane&7)*16; tile rows
  // step by 8 per GLDS so (row&7)==(lane>>3): swizzle is a per-lane constant.
  const int srow = lane >> 3;
  const int swze = (((lane & 7) * 16) ^ (srow << 4)) >> 1;  // u16 elems
  const u16* Kg = K + ((size_t)(b * 2048 + wave * 16 + srow)) * 1024 + h * 64 + swze;
  const u16* Vg = Vt + ((size_t)(bh * 64 + wave * 16 + srow)) * 2048 + swze;
  u16* kdst0 = &K_lds[(wave * 16 + 0) * 64];
  u16* kdst1 = &K_lds[(wave * 16 + 8) * 64];
  u16* vdst0 = &V_lds[(wave * 16 + 0) * 64];
  u16* vdst1 = &V_lds[(wave * 16 + 8) * 64];

  const float CSC = 0.125f * 1.44269504f;  // scale * log2(e)
  f32x4 acc[4] = {};
  float mrun = -1e30f, lsum = 0.f;

  for (int kt = 0; kt < 2048; kt += 64) {
    GLDS(Kg + (size_t)kt * 1024, kdst0);
    GLDS(Kg + (size_t)(kt + 8) * 1024, kdst1);
    GLDS(Vg + kt, vdst0);
    GLDS(Vg + kt + 8 * 2048, vdst1);
    __syncthreads();

    // --- S^T = K * Q^T (keys x qrows), 16 keys per sub ---
    f32x4 sf[4];
#pragma unroll
    for (int sub = 0; sub < 4; ++sub) {
      const int krow = sub * 16 + a15;
      const char* kp = (const char*)&K_lds[krow * 64];
      const int swz = (krow & 7) << 4;
      const bf16x8 k0 = *(const bf16x8*)(kp + ((g * 16) ^ swz));
      const bf16x8 k1 = *(const bf16x8*)(kp + ((g * 16 + 64) ^ swz));
      f32x4 s = {0.f, 0.f, 0.f, 0.f};
      s = __builtin_amdgcn_mfma_f32_16x16x32_bf16(k0, qf0, s, 0, 0, 0);
      s = __builtin_amdgcn_mfma_f32_16x16x32_bf16(k1, qf1, s, 0, 0, 0);
      sf[sub] = s;
    }
    // --- combined score s2 = s*CSC + log2(policy); online max in log2 domain ---
    float s2[16];
#pragma unroll
    for (int sub = 0; sub < 4; ++sub) {
      const float4 lp = *(const float4*)&l2p[b * 2048 + kt + sub * 16 + g * 4];
      s2[sub * 4 + 0] = fmaf(sf[sub][0], CSC, lp.x);
      s2[sub * 4 + 1] = fmaf(sf[sub][1], CSC, lp.y);
      s2[sub * 4 + 2] = fmaf(sf[sub][2], CSC, lp.z);
      s2[sub * 4 + 3] = fmaf(sf[sub][3], CSC, lp.w);
    }
    float mt = fmaxf(fmaxf(s2[0], s2[1]), s2[2]);
    const float t1 = fmaxf(fmaxf(s2[3], s2[4]), s2[5]);
    const float t2 = fmaxf(fmaxf(s2[6], s2[7]), s2[8]);
    const float t3 = fmaxf(fmaxf(s2[9], s2[10]), s2[11]);
    const float t4 = fmaxf(fmaxf(s2[12], s2[13]), s2[14]);
    mt = fmaxf(fmaxf(mt, t1), fmaxf(t2, fmaxf(t3, fmaxf(t4, s2[15]))));
    mt = fmaxf(mt, __shfl_xor(mt, 16));
    mt = fmaxf(mt, __shfl_xor(mt, 32));
    // --- defer-max: rescale only when the max grows by > 8 (rare) ---
    if (__any(mt > mrun + 8.f)) {
      const float mnew = fmaxf(mrun, mt);
      const float fs = __builtin_amdgcn_exp2f(mrun - mnew);
      mrun = mnew;
      lsum *= fs;
      const float fs0 = __shfl(fs, g * 4 + 0);
      const float fs1 = __shfl(fs, g * 4 + 1);
      const float fs2 = __shfl(fs, g * 4 + 2);
      const float fs3 = __shfl(fs, g * 4 + 3);
#pragma unroll
      for (int ni = 0; ni < 4; ++ni) {
        acc[ni][0] *= fs0; acc[ni][1] *= fs1;
        acc[ni][2] *= fs2; acc[ni][3] *= fs3;
      }
    }
    // --- P = exp2(s2 - m), pack to bf16 via v_cvt_pk, per-lane partial lsum ---
#pragma unroll
    for (int sub = 0; sub < 4; ++sub) {
      const float e0 = __builtin_amdgcn_exp2f(s2[sub * 4 + 0] - mrun);
      const float e1 = __builtin_amdgcn_exp2f(s2[sub * 4 + 1] - mrun);
      const float e2 = __builtin_amdgcn_exp2f(s2[sub * 4 + 2] - mrun);
      const float e3 = __builtin_amdgcn_exp2f(s2[sub * 4 + 3] - mrun);
      lsum += (e0 + e1) + (e2 + e3);
      unsigned int w0, w1;
      asm("v_cvt_pk_bf16_f32 %0, %1, %2" : "=v"(w0) : "v"(e0), "v"(e1));
      asm("v_cvt_pk_bf16_f32 %0, %1, %2" : "=v"(w1) : "v"(e2), "v"(e3));
      uint2 w; w.x = w0; w.y = w1;
      *(uint2*)&pl[a15 * 72 + sub * 16 + g * 4] = w;
    }
    asm volatile("" ::: "memory");  // order P_lds writes before PV reads
    // --- PV: out += P(16xkeys) * V(keys x 64dd) ---
#pragma unroll
    for (int kc = 0; kc < 2; ++kc) {
      const bf16x8 pa = *(const bf16x8*)&pl[a15 * 72 + kc * 32 + g * 8];
#pragma unroll
      for (int ni = 0; ni < 4; ++ni) {
        const int vrow = ni * 16 + a15;
        const char* vp = (const char*)&V_lds[vrow * 64];
        const int vswz = (vrow & 7) << 4;
        const bf16x8 vb = *(const bf16x8*)(vp + ((kc * 64 + g * 16) ^ vswz));
        acc[ni] = __builtin_amdgcn_mfma_f32_16x16x32_bf16(pa, vb, acc[ni], 0, 0, 0);
      }
    }
    __syncthreads();  // all LDS reads done before next stage overwrites
  }
  // cross-lane lsum reduction (once)
  lsum += __shfl_xor(lsum, 16);
  lsum += __shfl_xor(lsum, 32);
  const float li0 = 1.f / (__shfl(lsum, g * 4 + 0) + 1e-30f);
  const float li1 = 1.f / (__shfl(lsum, g * 4 + 1) + 1e-30f);
  const float li2 = 1.f / (__shfl(lsum, g * 4 + 2) + 1e-30f);
  const float li3 = 1.f / (__shfl(lsum, g * 4 + 3) + 1e-30f);
  const int obase = (b * 2048 + qx * 64 + wave * 16 + g * 4) * 1024 + h * 64 + a15;
#pragma unroll
  for (int ni = 0; ni < 4; ++ni) {
    O[obase + 0 * 1024 + ni * 16] = f2b(acc[ni][0] * li0);
    O[obase + 1 * 1024 + ni * 16] = f2b(acc[ni][1] * li1);
    O[obase + 2 * 1024 + ni * 16] = f2b(acc[ni][2] * li2);
    O[obase + 3 * 1024 + ni * 16] = f2b(acc[ni][3] * li3);
  }
}

extern "C" void kernel_launch(void* const* d_in, const int* in_sizes, int n_in,
                              void* d_out, int out_size, void* d_ws, size_t ws_size,
                              hipStream_t stream) {
  (void)in_sizes; (void)n_in; (void)out_size; (void)ws_size;
  const float* x   = (const float*)d_in[0];
  const float* xo  = (const float*)d_in[1];
  const float* dec = (const float*)d_in[2];
  const float* Wq  = (const float*)d_in[3];
  const float* Wk  = (const float*)d_in[4];
  const float* Wv  = (const float*)d_in[5];
  const float* Wp  = (const float*)d_in[6];
  float* out = (float*)d_out;   // reference output dtype is float32

  // ws layout (50 MB + 32KB):
  //   Wt  @  0MB (2MB)   reused for all four transposed bf16 weights
  //   Qb  @  2MB (16MB)  Q bf16, later overwritten in-place by attention out
  //   Kb  @ 18MB (16MB)  K bf16
  //   Vtb @ 34MB (16MB)  V^T bf16 (B,H,d,N), written directly by gemm epilogue
  //   l2p @ 50MB (32KB)  log2(1-decisions) f32
  char* ws = (char*)d_ws;
  u16* Wt    = (u16*)(ws + ((size_t)0 << 20));
  u16* Qb    = (u16*)(ws + ((size_t)2 << 20));
  u16* Kb    = (u16*)(ws + ((size_t)18 << 20));
  u16* Vtb   = (u16*)(ws + ((size_t)34 << 20));
  float* l2p = (float*)(ws + ((size_t)50 << 20));

  const dim3 blk(256);
  prep_l2p<<<dim3(32), blk, 0, stream>>>(dec, l2p);

  transpose_w<<<dim3(32, 32), blk, 0, stream>>>(Wq, Wt);
  gemm_bt<0, float, u16><<<dim3(64, 8), blk, 0, stream>>>(x, Wt, Qb);

  transpose_w<<<dim3(32, 32), blk, 0, stream>>>(Wk, Wt);
  gemm_bt<0, float, u16><<<dim3(64, 8), blk, 0, stream>>>(xo, Wt, Kb);

  transpose_w<<<dim3(32, 32), blk, 0, stream>>>(Wv, Wt);
  gemm_bt<1, float, u16><<<dim3(64, 8), blk, 0, stream>>>(xo, Wt, Vtb);

  transpose_w<<<dim3(32, 32), blk, 0, stream>>>(Wp, Wt);

  attn_kernel<<<dim3(2048), blk, 0, stream>>>(Qb, Kb, Vtb, l2p, Qb);

  gemm_bt<0, u16, float><<<dim3(64, 8), blk, 0, stream>>>(Qb, Wt, out);
}

// Round 8
// 264.219 us; speedup vs baseline: 2.3267x; 1.1054x over previous
//
#include <hip/hip_runtime.h>

typedef unsigned short u16;
typedef __attribute__((ext_vector_type(8))) short bf16x8;
typedef __attribute__((ext_vector_type(4))) short s16x4;
typedef __attribute__((ext_vector_type(4))) float f32x4;

#define GLDS(g, l) __builtin_amdgcn_global_load_lds( \
    (const __attribute__((address_space(1))) unsigned int*)(g), \
    (__attribute__((address_space(3))) unsigned int*)(l), 16, 0, 0)

__device__ __forceinline__ u16 f2b(float f) {
  unsigned int x = __float_as_uint(f);
  return (u16)((x + 0x7fffu + ((x >> 16) & 1u)) >> 16);
}
__device__ __forceinline__ bf16x8 cvt8(float4 a, float4 b) {
  bf16x8 r;
  r[0] = (short)f2b(a.x); r[1] = (short)f2b(a.y);
  r[2] = (short)f2b(a.z); r[3] = (short)f2b(a.w);
  r[4] = (short)f2b(b.x); r[5] = (short)f2b(b.y);
  r[6] = (short)f2b(b.z); r[7] = (short)f2b(b.w);
  return r;
}

// ---- all 4 weight transposes in one launch: Wt[n][k] = bf16(W[k][n]) ----
__global__ __launch_bounds__(256) void transpose_w4(
    const float* __restrict__ W0, const float* __restrict__ W1,
    const float* __restrict__ W2, const float* __restrict__ W3,
    u16* __restrict__ D0, u16* __restrict__ D1,
    u16* __restrict__ D2, u16* __restrict__ D3) {
  const int z = blockIdx.z;
  const float* W = (z == 0) ? W0 : (z == 1) ? W1 : (z == 2) ? W2 : W3;
  u16* Wt = (z == 0) ? D0 : (z == 1) ? D1 : (z == 2) ? D2 : D3;
  __shared__ u16 tile[32][33];
  const int tx = threadIdx.x & 31, ty = threadIdx.x >> 5;
  const int r0 = blockIdx.y * 32, c0 = blockIdx.x * 32;
#pragma unroll
  for (int i = 0; i < 32; i += 8)
    tile[ty + i][tx] = f2b(W[(r0 + ty + i) * 1024 + c0 + tx]);
  __syncthreads();
#pragma unroll
  for (int i = 0; i < 32; i += 8)
    Wt[(c0 + ty + i) * 1024 + r0 + tx] = tile[tx][ty + i];
}

// ---------------- C = A(8192x1024) * Bt^T, double-buffered 2-phase ----------------
// A: f32 (reg-staged->bf16 LDS) or bf16 (global_load_lds). B: bf16 GLDS w16.
// 128x128 tile, BK=32, 4 waves, 16x16x32 MFMA. Prefetch K-step t+1 during compute(t).
// EPI==0: C row-major (OT u16->bf16 / float->f32).
// EPI==2: fused K|V gemm (Bt has 2048 rows = Wk^T|Wv^T): blockIdx.y<8 -> K row-major
//         into C; y>=8 -> V^T per head into C2: Vt[(b,h),dd,n].
template <int EPI, typename AT, typename OT>
__global__ __launch_bounds__(256) void gemm_bt(const AT* __restrict__ A,
                                               const u16* __restrict__ Bt,
                                               OT* __restrict__ C,
                                               u16* __restrict__ C2) {
  __shared__ u16 As[2][128 * 32];
  __shared__ u16 Bs[2][128 * 32];
  const int t = threadIdx.x;
  const int wave = t >> 6, lane = t & 63;
  const int g = lane >> 4, a15 = lane & 15;
  const int wr = wave >> 1, wc = wave & 1;
  const int row0 = t >> 2;            // 0..63
  const int col0 = (t & 3) * 8;       // 0,8,16,24
  const int abase = (blockIdx.x * 128 + row0) * 1024 + col0;
  const int bbase = (blockIdx.y * 128 + row0) * 1024 + col0;

  f32x4 acc[4][4] = {};

  // ---- prologue: stage K-step 0 into buffer 0 ----
  if constexpr (sizeof(AT) == 4) {
    const float* Ag = (const float*)A + abase;
    GLDS(Bt + bbase, &Bs[0][wave * 512]);
    GLDS(Bt + bbase + 64 * 1024, &Bs[0][2048 + wave * 512]);
    const float4 x0 = *(const float4*)(Ag);
    const float4 x1 = *(const float4*)(Ag + 4);
    const float4 y0 = *(const float4*)(Ag + 64 * 1024);
    const float4 y1 = *(const float4*)(Ag + 64 * 1024 + 4);
    *(bf16x8*)&As[0][row0 * 32 + col0] = cvt8(x0, x1);
    *(bf16x8*)&As[0][(row0 + 64) * 32 + col0] = cvt8(y0, y1);
  } else {
    GLDS((const u16*)A + abase, &As[0][wave * 512]);
    GLDS((const u16*)A + abase + 64 * 1024, &As[0][2048 + wave * 512]);
    GLDS(Bt + bbase, &Bs[0][wave * 512]);
    GLDS(Bt + bbase + 64 * 1024, &Bs[0][2048 + wave * 512]);
  }
  __syncthreads();

  for (int ki = 0; ki < 32; ++ki) {
    const int cur = ki & 1, nxt = cur ^ 1;
    const int ktn = (ki + 1) * 32;
    const bool pf = ki < 31;
    float4 x0, x1, y0, y1;
    if (pf) {
      if constexpr (sizeof(AT) == 4) {
        const float* Ag = (const float*)A + abase + ktn;
        GLDS(Bt + bbase + ktn, &Bs[nxt][wave * 512]);
        GLDS(Bt + bbase + 64 * 1024 + ktn, &Bs[nxt][2048 + wave * 512]);
        x0 = *(const float4*)(Ag);
        x1 = *(const float4*)(Ag + 4);
        y0 = *(const float4*)(Ag + 64 * 1024);
        y1 = *(const float4*)(Ag + 64 * 1024 + 4);
      } else {
        GLDS((const u16*)A + abase + ktn, &As[nxt][wave * 512]);
        GLDS((const u16*)A + abase + 64 * 1024 + ktn, &As[nxt][2048 + wave * 512]);
        GLDS(Bt + bbase + ktn, &Bs[nxt][wave * 512]);
        GLDS(Bt + bbase + 64 * 1024 + ktn, &Bs[nxt][2048 + wave * 512]);
      }
    }
    // ---- compute on buffer cur ----
    bf16x8 af[4], bfr[4];
#pragma unroll
    for (int mi = 0; mi < 4; ++mi)
      af[mi] = *(const bf16x8*)&As[cur][(wr * 64 + mi * 16 + a15) * 32 + g * 8];
#pragma unroll
    for (int ni = 0; ni < 4; ++ni)
      bfr[ni] = *(const bf16x8*)&Bs[cur][(wc * 64 + ni * 16 + a15) * 32 + g * 8];
#pragma unroll
    for (int mi = 0; mi < 4; ++mi)
#pragma unroll
      for (int ni = 0; ni < 4; ++ni)
        acc[mi][ni] = __builtin_amdgcn_mfma_f32_16x16x32_bf16(af[mi], bfr[ni], acc[mi][ni], 0, 0, 0);
    if (pf) {
      if constexpr (sizeof(AT) == 4) {
        *(bf16x8*)&As[nxt][row0 * 32 + col0] = cvt8(x0, x1);
        *(bf16x8*)&As[nxt][(row0 + 64) * 32 + col0] = cvt8(y0, y1);
      }
    }
    __syncthreads();
  }

  const int crow = blockIdx.x * 128 + wr * 64 + g * 4;
  const int ccol = blockIdx.y * 128 + wc * 64 + a15;
  if constexpr (EPI == 0) {
#pragma unroll
    for (int mi = 0; mi < 4; ++mi)
#pragma unroll
      for (int ni = 0; ni < 4; ++ni)
#pragma unroll
        for (int r = 0; r < 4; ++r) {
          const float v = acc[mi][ni][r];
          if constexpr (sizeof(OT) == 2)
            C[(crow + mi * 16 + r) * 1024 + ccol + ni * 16] = (OT)f2b(v);
          else
            C[(crow + mi * 16 + r) * 1024 + ccol + ni * 16] = (OT)v;
        }
  } else {
    if (blockIdx.y < 8) {
      // K part: row-major bf16
#pragma unroll
      for (int mi = 0; mi < 4; ++mi)
#pragma unroll
        for (int ni = 0; ni < 4; ++ni)
#pragma unroll
          for (int r = 0; r < 4; ++r)
            ((u16*)C)[(crow + mi * 16 + r) * 1024 + ccol + ni * 16] = f2b(acc[mi][ni][r]);
    } else {
      // V part: Vt[((b*16+h)*64 + dd)*2048 + n], col c = ccol - 1024
#pragma unroll
      for (int mi = 0; mi < 4; ++mi) {
        const int n = crow + mi * 16;
        const int bq = n >> 11;
        const int nl = n & 2047;
#pragma unroll
        for (int ni = 0; ni < 4; ++ni) {
          const int c = ccol + ni * 16 - 1024;
          s16x4 v4;
          v4[0] = (short)f2b(acc[mi][ni][0]);
          v4[1] = (short)f2b(acc[mi][ni][1]);
          v4[2] = (short)f2b(acc[mi][ni][2]);
          v4[3] = (short)f2b(acc[mi][ni][3]);
          *(s16x4*)&C2[(((bq << 4) + (c >> 6)) * 64 + (c & 63)) * 2048 + nl] = v4;
        }
      }
    }
  }
}

// ---------------- flash attention, fixed-shift log2-domain softmax ----------------
// 1-D grid 2048, XCD remap (T1): head bh owned by one XCD -> K/V L2-resident.
// 4 waves/block, 16 q-rows/wave, KV step 64, double-buffered K/V with prefetch
// (stage t+1 before compute t, ONE barrier per tile). Swapped QK^T. Softmax is
// exact with fixed shift m=0: out = sum(exp2(s2)*v)/sum(exp2(s2)) where
// s2 = qk*scale*log2e + log2(1-dec) (softmax shift-invariance; EPS terms <=1e-8).
// O aliases Q (disjoint per-block read/write regions, dep through acc).
__global__ __launch_bounds__(256) void attn_kernel(
    const u16* Q, const u16* __restrict__ K,
    const u16* __restrict__ Vt, const float* __restrict__ dec,
    u16* O) {
  const int f = blockIdx.x;
  const int bh = (f & 7) * 8 + (f >> 8);     // 8 heads per XCD
  const int qx = (f >> 3) & 31;
  const int b = bh >> 4, h = bh & 15;
  __shared__ u16 K_lds[2][64 * 64];  // [key][dim] XOR-swizzled rows, 8KB each
  __shared__ u16 V_lds[2][64 * 64];  // [dd][key] XOR-swizzled rows, 8KB each
  __shared__ __align__(16) u16 P_lds[4][16 * 72];
  __shared__ float l2p_lds[2048];

  const int wave = threadIdx.x >> 6, lane = threadIdx.x & 63;
  const int g = lane >> 4, a15 = lane & 15;
  u16* pl = &P_lds[wave][0];

  // l2p = log2(1 - dec) computed in-block (8 keys/thread)
  {
    const int i0 = threadIdx.x * 8;
    const float4 d0 = *(const float4*)&dec[b * 2048 + i0];
    const float4 d1 = *(const float4*)&dec[b * 2048 + i0 + 4];
    float4 o0, o1;
    o0.x = __log2f(fmaxf(1.f - d0.x, 1e-38f));
    o0.y = __log2f(fmaxf(1.f - d0.y, 1e-38f));
    o0.z = __log2f(fmaxf(1.f - d0.z, 1e-38f));
    o0.w = __log2f(fmaxf(1.f - d0.w, 1e-38f));
    o1.x = __log2f(fmaxf(1.f - d1.x, 1e-38f));
    o1.y = __log2f(fmaxf(1.f - d1.y, 1e-38f));
    o1.z = __log2f(fmaxf(1.f - d1.z, 1e-38f));
    o1.w = __log2f(fmaxf(1.f - d1.w, 1e-38f));
    *(float4*)&l2p_lds[i0] = o0;
    *(float4*)&l2p_lds[i0 + 4] = o1;
  }

  const int qrow = qx * 64 + wave * 16 + a15;
  const int qoff = (b * 2048 + qrow) * 1024 + h * 64 + g * 8;
  const bf16x8 qf0 = *(const bf16x8*)&Q[qoff];
  const bf16x8 qf1 = *(const bf16x8*)&Q[qoff + 32];

  // staging mapping: row-in-8 = lane>>3, colByte = (lane&7)*16; tile rows step
  // by 8 per GLDS so (row&7)==(lane>>3): source swizzle is a per-lane constant.
  const int srow = lane >> 3;
  const int swze = (((lane & 7) * 16) ^ (srow << 4)) >> 1;  // u16 elems
  const u16* Kg = K + ((size_t)(b * 2048 + wave * 16 + srow)) * 1024 + h * 64 + swze;
  const u16* Vg = Vt + ((size_t)(bh * 64 + wave * 16 + srow)) * 2048 + swze;

  // ---- prologue: stage tile 0 into buffer 0 ----
  GLDS(Kg, &K_lds[0][(wave * 16 + 0) * 64]);
  GLDS(Kg + (size_t)8 * 1024, &K_lds[0][(wave * 16 + 8) * 64]);
  GLDS(Vg, &V_lds[0][(wave * 16 + 0) * 64]);
  GLDS(Vg + 8 * 2048, &V_lds[0][(wave * 16 + 8) * 64]);
  __syncthreads();

  const float CSC = 0.125f * 1.44269504f;  // scale * log2(e)
  f32x4 acc[4] = {};
  f32x4 ls4 = {0.f, 0.f, 0.f, 0.f};

  for (int it = 0; it < 32; ++it) {
    const int cur = it & 1, nxt = cur ^ 1;
    if (it < 31) {
      const int ktn = (it + 1) * 64;
      GLDS(Kg + (size_t)ktn * 1024, &K_lds[nxt][(wave * 16 + 0) * 64]);
      GLDS(Kg + (size_t)(ktn + 8) * 1024, &K_lds[nxt][(wave * 16 + 8) * 64]);
      GLDS(Vg + ktn, &V_lds[nxt][(wave * 16 + 0) * 64]);
      GLDS(Vg + ktn + 8 * 2048, &V_lds[nxt][(wave * 16 + 8) * 64]);
    }
    const int kt = it * 64;
    // --- S^T = K * Q^T ---
    f32x4 sf[4];
#pragma unroll
    for (int sub = 0; sub < 4; ++sub) {
      const int krow = sub * 16 + a15;
      const char* kp = (const char*)&K_lds[cur][krow * 64];
      const int swz = (krow & 7) << 4;
      const bf16x8 k0 = *(const bf16x8*)(kp + ((g * 16) ^ swz));
      const bf16x8 k1 = *(const bf16x8*)(kp + ((g * 16 + 64) ^ swz));
      f32x4 s = {0.f, 0.f, 0.f, 0.f};
      s = __builtin_amdgcn_mfma_f32_16x16x32_bf16(k0, qf0, s, 0, 0, 0);
      s = __builtin_amdgcn_mfma_f32_16x16x32_bf16(k1, qf1, s, 0, 0, 0);
      sf[sub] = s;
    }
    // --- straight-line softmax: e = exp2(s*CSC + l2p), pack bf16 ---
#pragma unroll
    for (int sub = 0; sub < 4; ++sub) {
      const float4 lp = *(const float4*)&l2p_lds[kt + sub * 16 + g * 4];
      const float e0 = __builtin_amdgcn_exp2f(fmaf(sf[sub][0], CSC, lp.x));
      const float e1 = __builtin_amdgcn_exp2f(fmaf(sf[sub][1], CSC, lp.y));
      const float e2 = __builtin_amdgcn_exp2f(fmaf(sf[sub][2], CSC, lp.z));
      const float e3 = __builtin_amdgcn_exp2f(fmaf(sf[sub][3], CSC, lp.w));
      ls4[0] += e0; ls4[1] += e1; ls4[2] += e2; ls4[3] += e3;
      unsigned int w0, w1;
      asm("v_cvt_pk_bf16_f32 %0, %1, %2" : "=v"(w0) : "v"(e0), "v"(e1));
      asm("v_cvt_pk_bf16_f32 %0, %1, %2" : "=v"(w1) : "v"(e2), "v"(e3));
      uint2 w; w.x = w0; w.y = w1;
      *(uint2*)&pl[a15 * 72 + sub * 16 + g * 4] = w;
    }
    asm volatile("" ::: "memory");  // order P_lds writes before PV reads
    // --- PV ---
#pragma unroll
    for (int kc = 0; kc < 2; ++kc) {
      const bf16x8 pa = *(const bf16x8*)&pl[a15 * 72 + kc * 32 + g * 8];
#pragma unroll
      for (int ni = 0; ni < 4; ++ni) {
        const int vrow = ni * 16 + a15;
        const char* vp = (const char*)&V_lds[cur][vrow * 64];
        const int vswz = (vrow & 7) << 4;
        const bf16x8 vb = *(const bf16x8*)(vp + ((kc * 64 + g * 16) ^ vswz));
        acc[ni] = __builtin_amdgcn_mfma_f32_16x16x32_bf16(pa, vb, acc[ni], 0, 0, 0);
      }
    }
    __syncthreads();  // drains prefetch (landed under compute) + read/write fence
  }
  // row sums: lane holds partials for qrow=a15; reduce across g-groups once
  float lsum = (ls4[0] + ls4[1]) + (ls4[2] + ls4[3]);
  lsum += __shfl_xor(lsum, 16);
  lsum += __shfl_xor(lsum, 32);
  const float li0 = 1.f / (__shfl(lsum, g * 4 + 0) + 1e-30f);
  const float li1 = 1.f / (__shfl(lsum, g * 4 + 1) + 1e-30f);
  const float li2 = 1.f / (__shfl(lsum, g * 4 + 2) + 1e-30f);
  const float li3 = 1.f / (__shfl(lsum, g * 4 + 3) + 1e-30f);
  const int obase = (b * 2048 + qx * 64 + wave * 16 + g * 4) * 1024 + h * 64 + a15;
#pragma unroll
  for (int ni = 0; ni < 4; ++ni) {
    O[obase + 0 * 1024 + ni * 16] = f2b(acc[ni][0] * li0);
    O[obase + 1 * 1024 + ni * 16] = f2b(acc[ni][1] * li1);
    O[obase + 2 * 1024 + ni * 16] = f2b(acc[ni][2] * li2);
    O[obase + 3 * 1024 + ni * 16] = f2b(acc[ni][3] * li3);
  }
}

extern "C" void kernel_launch(void* const* d_in, const int* in_sizes, int n_in,
                              void* d_out, int out_size, void* d_ws, size_t ws_size,
                              hipStream_t stream) {
  (void)in_sizes; (void)n_in; (void)out_size; (void)ws_size;
  const float* x   = (const float*)d_in[0];
  const float* xo  = (const float*)d_in[1];
  const float* dec = (const float*)d_in[2];
  const float* Wq  = (const float*)d_in[3];
  const float* Wk  = (const float*)d_in[4];
  const float* Wv  = (const float*)d_in[5];
  const float* Wp  = (const float*)d_in[6];
  float* out = (float*)d_out;

  // ws layout (40 MB): Wqt@0(2M) | Wkvt@2M(4M: Wk^T rows 0-1023, Wv^T rows 1024-2047)
  //                    | Wpt@6M(2M) | Qb@8M(16M, becomes O) | Vtb@24M(16M)
  // K parked in d_out (dead until final GEMM overwrites it).
  char* ws = (char*)d_ws;
  u16* Wqt  = (u16*)(ws + ((size_t)0 << 20));
  u16* Wkvt = (u16*)(ws + ((size_t)2 << 20));
  u16* Wpt  = (u16*)(ws + ((size_t)6 << 20));
  u16* Qb   = (u16*)(ws + ((size_t)8 << 20));
  u16* Vtb  = (u16*)(ws + ((size_t)24 << 20));
  u16* Kb   = (u16*)d_out;

  const dim3 blk(256);
  transpose_w4<<<dim3(32, 32, 4), blk, 0, stream>>>(
      Wq, Wk, Wv, Wp, Wqt, Wkvt, Wkvt + 1024 * 1024, Wpt);

  gemm_bt<0, float, u16><<<dim3(64, 8), blk, 0, stream>>>(x, Wqt, Qb, nullptr);
  gemm_bt<2, float, u16><<<dim3(64, 16), blk, 0, stream>>>(xo, Wkvt, Kb, Vtb);

  attn_kernel<<<dim3(2048), blk, 0, stream>>>(Qb, Kb, Vtb, dec, Qb);

  gemm_bt<0, u16, float><<<dim3(64, 8), blk, 0, stream>>>(Qb, Wpt, out, nullptr);
}

// Round 9
// 250.302 us; speedup vs baseline: 2.4561x; 1.0556x over previous
//
#include <hip/hip_runtime.h>

typedef unsigned short u16;
typedef __attribute__((ext_vector_type(8))) short bf16x8;
typedef __attribute__((ext_vector_type(4))) short s16x4;
typedef __attribute__((ext_vector_type(4))) float f32x4;

#define GLDS(g, l) __builtin_amdgcn_global_load_lds( \
    (const __attribute__((address_space(1))) unsigned int*)(g), \
    (__attribute__((address_space(3))) unsigned int*)(l), 16, 0, 0)

__device__ __forceinline__ u16 f2b(float f) {
  unsigned int x = __float_as_uint(f);
  return (u16)((x + 0x7fffu + ((x >> 16) & 1u)) >> 16);
}
__device__ __forceinline__ bf16x8 cvt8(float4 a, float4 b) {
  bf16x8 r;
  r[0] = (short)f2b(a.x); r[1] = (short)f2b(a.y);
  r[2] = (short)f2b(a.z); r[3] = (short)f2b(a.w);
  r[4] = (short)f2b(b.x); r[5] = (short)f2b(b.y);
  r[6] = (short)f2b(b.z); r[7] = (short)f2b(b.w);
  return r;
}

// ---- all 4 weight transposes in one launch: Wt[n][k] = bf16(W[k][n]) ----
__global__ __launch_bounds__(256) void transpose_w4(
    const float* __restrict__ W0, const float* __restrict__ W1,
    const float* __restrict__ W2, const float* __restrict__ W3,
    u16* __restrict__ D0, u16* __restrict__ D1,
    u16* __restrict__ D2, u16* __restrict__ D3) {
  const int z = blockIdx.z;
  const float* W = (z == 0) ? W0 : (z == 1) ? W1 : (z == 2) ? W2 : W3;
  u16* Wt = (z == 0) ? D0 : (z == 1) ? D1 : (z == 2) ? D2 : D3;
  __shared__ u16 tile[32][33];
  const int tx = threadIdx.x & 31, ty = threadIdx.x >> 5;
  const int r0 = blockIdx.y * 32, c0 = blockIdx.x * 32;
#pragma unroll
  for (int i = 0; i < 32; i += 8)
    tile[ty + i][tx] = f2b(W[(r0 + ty + i) * 1024 + c0 + tx]);
  __syncthreads();
#pragma unroll
  for (int i = 0; i < 32; i += 8)
    Wt[(c0 + ty + i) * 1024 + r0 + tx] = tile[tx][ty + i];
}

// ---------------- C = A(8192x1024) * Bt^T, double-buffered 2-phase ----------------
// A: f32 (reg-staged->bf16 LDS) or bf16 (global_load_lds). B: bf16 GLDS w16.
// 128x128 tile, BK=32, 4 waves, 16x16x32 MFMA. Prefetch K-step t+1 during compute(t).
// EPI==0: C row-major (OT u16->bf16 / float->f32).
// EPI==2: fused K|V gemm (Bt has 2048 rows = Wk^T|Wv^T): blockIdx.y<8 -> K row-major
//         into C; y>=8 -> V^T per head into C2: Vt[(b,h),dd,n].
template <int EPI, typename AT, typename OT>
__global__ __launch_bounds__(256) void gemm_bt(const AT* __restrict__ A,
                                               const u16* __restrict__ Bt,
                                               OT* __restrict__ C,
                                               u16* __restrict__ C2) {
  __shared__ u16 As[2][128 * 32];
  __shared__ u16 Bs[2][128 * 32];
  const int t = threadIdx.x;
  const int wave = t >> 6, lane = t & 63;
  const int g = lane >> 4, a15 = lane & 15;
  const int wr = wave >> 1, wc = wave & 1;
  const int row0 = t >> 2;            // 0..63
  const int col0 = (t & 3) * 8;       // 0,8,16,24
  const int abase = (blockIdx.x * 128 + row0) * 1024 + col0;
  const int bbase = (blockIdx.y * 128 + row0) * 1024 + col0;

  f32x4 acc[4][4] = {};

  // ---- prologue: stage K-step 0 into buffer 0 ----
  if constexpr (sizeof(AT) == 4) {
    const float* Ag = (const float*)A + abase;
    GLDS(Bt + bbase, &Bs[0][wave * 512]);
    GLDS(Bt + bbase + 64 * 1024, &Bs[0][2048 + wave * 512]);
    const float4 x0 = *(const float4*)(Ag);
    const float4 x1 = *(const float4*)(Ag + 4);
    const float4 y0 = *(const float4*)(Ag + 64 * 1024);
    const float4 y1 = *(const float4*)(Ag + 64 * 1024 + 4);
    *(bf16x8*)&As[0][row0 * 32 + col0] = cvt8(x0, x1);
    *(bf16x8*)&As[0][(row0 + 64) * 32 + col0] = cvt8(y0, y1);
  } else {
    GLDS((const u16*)A + abase, &As[0][wave * 512]);
    GLDS((const u16*)A + abase + 64 * 1024, &As[0][2048 + wave * 512]);
    GLDS(Bt + bbase, &Bs[0][wave * 512]);
    GLDS(Bt + bbase + 64 * 1024, &Bs[0][2048 + wave * 512]);
  }
  __syncthreads();

  for (int ki = 0; ki < 32; ++ki) {
    const int cur = ki & 1, nxt = cur ^ 1;
    const int ktn = (ki + 1) * 32;
    const bool pf = ki < 31;
    float4 x0, x1, y0, y1;
    if (pf) {
      if constexpr (sizeof(AT) == 4) {
        const float* Ag = (const float*)A + abase + ktn;
        GLDS(Bt + bbase + ktn, &Bs[nxt][wave * 512]);
        GLDS(Bt + bbase + 64 * 1024 + ktn, &Bs[nxt][2048 + wave * 512]);
        x0 = *(const float4*)(Ag);
        x1 = *(const float4*)(Ag + 4);
        y0 = *(const float4*)(Ag + 64 * 1024);
        y1 = *(const float4*)(Ag + 64 * 1024 + 4);
      } else {
        GLDS((const u16*)A + abase + ktn, &As[nxt][wave * 512]);
        GLDS((const u16*)A + abase + 64 * 1024 + ktn, &As[nxt][2048 + wave * 512]);
        GLDS(Bt + bbase + ktn, &Bs[nxt][wave * 512]);
        GLDS(Bt + bbase + 64 * 1024 + ktn, &Bs[nxt][2048 + wave * 512]);
      }
    }
    // ---- compute on buffer cur ----
    bf16x8 af[4], bfr[4];
#pragma unroll
    for (int mi = 0; mi < 4; ++mi)
      af[mi] = *(const bf16x8*)&As[cur][(wr * 64 + mi * 16 + a15) * 32 + g * 8];
#pragma unroll
    for (int ni = 0; ni < 4; ++ni)
      bfr[ni] = *(const bf16x8*)&Bs[cur][(wc * 64 + ni * 16 + a15) * 32 + g * 8];
#pragma unroll
    for (int mi = 0; mi < 4; ++mi)
#pragma unroll
      for (int ni = 0; ni < 4; ++ni)
        acc[mi][ni] = __builtin_amdgcn_mfma_f32_16x16x32_bf16(af[mi], bfr[ni], acc[mi][ni], 0, 0, 0);
    if (pf) {
      if constexpr (sizeof(AT) == 4) {
        *(bf16x8*)&As[nxt][row0 * 32 + col0] = cvt8(x0, x1);
        *(bf16x8*)&As[nxt][(row0 + 64) * 32 + col0] = cvt8(y0, y1);
      }
    }
    __syncthreads();
  }

  const int crow = blockIdx.x * 128 + wr * 64 + g * 4;
  const int ccol = blockIdx.y * 128 + wc * 64 + a15;
  if constexpr (EPI == 0) {
#pragma unroll
    for (int mi = 0; mi < 4; ++mi)
#pragma unroll
      for (int ni = 0; ni < 4; ++ni)
#pragma unroll
        for (int r = 0; r < 4; ++r) {
          const float v = acc[mi][ni][r];
          if constexpr (sizeof(OT) == 2)
            C[(crow + mi * 16 + r) * 1024 + ccol + ni * 16] = (OT)f2b(v);
          else
            C[(crow + mi * 16 + r) * 1024 + ccol + ni * 16] = (OT)v;
        }
  } else {
    if (blockIdx.y < 8) {
      // K part: row-major bf16
#pragma unroll
      for (int mi = 0; mi < 4; ++mi)
#pragma unroll
        for (int ni = 0; ni < 4; ++ni)
#pragma unroll
          for (int r = 0; r < 4; ++r)
            ((u16*)C)[(crow + mi * 16 + r) * 1024 + ccol + ni * 16] = f2b(acc[mi][ni][r]);
    } else {
      // V part: Vt[((b*16+h)*64 + dd)*2048 + n], col c = ccol - 1024
#pragma unroll
      for (int mi = 0; mi < 4; ++mi) {
        const int n = crow + mi * 16;
        const int bq = n >> 11;
        const int nl = n & 2047;
#pragma unroll
        for (int ni = 0; ni < 4; ++ni) {
          const int c = ccol + ni * 16 - 1024;
          s16x4 v4;
          v4[0] = (short)f2b(acc[mi][ni][0]);
          v4[1] = (short)f2b(acc[mi][ni][1]);
          v4[2] = (short)f2b(acc[mi][ni][2]);
          v4[3] = (short)f2b(acc[mi][ni][3]);
          *(s16x4*)&C2[(((bq << 4) + (c >> 6)) * 64 + (c & 63)) * 2048 + nl] = v4;
        }
      }
    }
  }
}

// ---------------- flash attention, fixed-shift log2-domain softmax ----------------
// grid 1024, XCD remap: head bh owned by one XCD -> K/V L2-resident.
// 4 waves/block, QBLK=32 q-rows per wave (128/block), KV step 64, double-buffered
// K/V with prefetch. KEY CHANGE vs r8: each K/V LDS fragment is read ONCE and fed
// to TWO MFMAs (two 16-row q-groups) -> K/V LDS-read traffic per q-row halves
// (LDS pipe was the r8 bottleneck: ~96KB/block/tile ~= 120us of LDS time).
// Softmax exact with fixed shift m=0 (shift-invariance; EPS terms <=1e-8).
// O aliases Q (each wave reads exactly the rows it finally overwrites).
__global__ __launch_bounds__(256) void attn_kernel(
    const u16* Q, const u16* __restrict__ K,
    const u16* __restrict__ Vt, const float* __restrict__ dec,
    u16* O) {
  const int f = blockIdx.x;
  const int bh = (f & 7) * 8 + ((f >> 3) & 7);   // 8 heads per XCD
  const int qx = f >> 6;                          // [0,16) q-tile of 128 rows
  const int b = bh >> 4, h = bh & 15;
  __shared__ u16 K_lds[2][64 * 64];  // [key][dim] XOR-swizzled rows, 8KB each
  __shared__ u16 V_lds[2][64 * 64];  // [dd][key] XOR-swizzled rows, 8KB each
  __shared__ __align__(16) u16 P_lds[4][32 * 72];  // per-wave 32 q x 64 keys
  __shared__ float l2p_lds[2048];

  const int wave = threadIdx.x >> 6, lane = threadIdx.x & 63;
  const int g = lane >> 4, a15 = lane & 15;
  u16* pl = &P_lds[wave][0];

  // l2p = log2(1 - dec) computed in-block (8 keys/thread)
  {
    const int i0 = threadIdx.x * 8;
    const float4 d0 = *(const float4*)&dec[b * 2048 + i0];
    const float4 d1 = *(const float4*)&dec[b * 2048 + i0 + 4];
    float4 o0, o1;
    o0.x = __log2f(fmaxf(1.f - d0.x, 1e-38f));
    o0.y = __log2f(fmaxf(1.f - d0.y, 1e-38f));
    o0.z = __log2f(fmaxf(1.f - d0.z, 1e-38f));
    o0.w = __log2f(fmaxf(1.f - d0.w, 1e-38f));
    o1.x = __log2f(fmaxf(1.f - d1.x, 1e-38f));
    o1.y = __log2f(fmaxf(1.f - d1.y, 1e-38f));
    o1.z = __log2f(fmaxf(1.f - d1.z, 1e-38f));
    o1.w = __log2f(fmaxf(1.f - d1.w, 1e-38f));
    *(float4*)&l2p_lds[i0] = o0;
    *(float4*)&l2p_lds[i0 + 4] = o1;
  }

  // Q fragments for two 16-row groups (rows qx*128 + wave*32 + qg*16 + a15)
  bf16x8 qf[2][2];
  {
    const int qr = (b * 2048 + qx * 128 + wave * 32 + a15) * 1024 + h * 64 + g * 8;
#pragma unroll
    for (int qg = 0; qg < 2; ++qg) {
      qf[qg][0] = *(const bf16x8*)&Q[qr + qg * 16 * 1024];
      qf[qg][1] = *(const bf16x8*)&Q[qr + qg * 16 * 1024 + 32];
    }
  }

  // staging mapping: row-in-8 = lane>>3, colByte = (lane&7)*16; tile rows step
  // by 8 per GLDS so (row&7)==(lane>>3): source swizzle is a per-lane constant.
  const int srow = lane >> 3;
  const int swze = (((lane & 7) * 16) ^ (srow << 4)) >> 1;  // u16 elems
  const u16* Kg = K + ((size_t)(b * 2048 + wave * 16 + srow)) * 1024 + h * 64 + swze;
  const u16* Vg = Vt + ((size_t)(bh * 64 + wave * 16 + srow)) * 2048 + swze;

  // ---- prologue: stage tile 0 into buffer 0 ----
  GLDS(Kg, &K_lds[0][(wave * 16 + 0) * 64]);
  GLDS(Kg + (size_t)8 * 1024, &K_lds[0][(wave * 16 + 8) * 64]);
  GLDS(Vg, &V_lds[0][(wave * 16 + 0) * 64]);
  GLDS(Vg + 8 * 2048, &V_lds[0][(wave * 16 + 8) * 64]);
  __syncthreads();

  const float CSC = 0.125f * 1.44269504f;  // scale * log2(e)
  f32x4 acc[2][4] = {};
  f32x4 ls[2] = {};

  for (int it = 0; it < 32; ++it) {
    const int cur = it & 1, nxt = cur ^ 1;
    if (it < 31) {
      const int ktn = (it + 1) * 64;
      GLDS(Kg + (size_t)ktn * 1024, &K_lds[nxt][(wave * 16 + 0) * 64]);
      GLDS(Kg + (size_t)(ktn + 8) * 1024, &K_lds[nxt][(wave * 16 + 8) * 64]);
      GLDS(Vg + ktn, &V_lds[nxt][(wave * 16 + 0) * 64]);
      GLDS(Vg + ktn + 8 * 2048, &V_lds[nxt][(wave * 16 + 8) * 64]);
    }
    const int kt = it * 64;
    // --- S^T = K * Q^T : each K fragment read once, used by both q-groups ---
    f32x4 sf[2][4];
#pragma unroll
    for (int sub = 0; sub < 4; ++sub) {
      const int krow = sub * 16 + a15;
      const char* kp = (const char*)&K_lds[cur][krow * 64];
      const int swz = (krow & 7) << 4;
      const bf16x8 k0 = *(const bf16x8*)(kp + ((g * 16) ^ swz));
      const bf16x8 k1 = *(const bf16x8*)(kp + ((g * 16 + 64) ^ swz));
#pragma unroll
      for (int qg = 0; qg < 2; ++qg) {
        f32x4 s = {0.f, 0.f, 0.f, 0.f};
        s = __builtin_amdgcn_mfma_f32_16x16x32_bf16(k0, qf[qg][0], s, 0, 0, 0);
        s = __builtin_amdgcn_mfma_f32_16x16x32_bf16(k1, qf[qg][1], s, 0, 0, 0);
        sf[qg][sub] = s;
      }
    }
    // --- straight-line softmax both groups: e = exp2(s*CSC + l2p) ---
#pragma unroll
    for (int qg = 0; qg < 2; ++qg) {
#pragma unroll
      for (int sub = 0; sub < 4; ++sub) {
        const float4 lp = *(const float4*)&l2p_lds[kt + sub * 16 + g * 4];
        const float e0 = __builtin_amdgcn_exp2f(fmaf(sf[qg][sub][0], CSC, lp.x));
        const float e1 = __builtin_amdgcn_exp2f(fmaf(sf[qg][sub][1], CSC, lp.y));
        const float e2 = __builtin_amdgcn_exp2f(fmaf(sf[qg][sub][2], CSC, lp.z));
        const float e3 = __builtin_amdgcn_exp2f(fmaf(sf[qg][sub][3], CSC, lp.w));
        ls[qg][0] += e0; ls[qg][1] += e1; ls[qg][2] += e2; ls[qg][3] += e3;
        unsigned int w0, w1;
        asm("v_cvt_pk_bf16_f32 %0, %1, %2" : "=v"(w0) : "v"(e0), "v"(e1));
        asm("v_cvt_pk_bf16_f32 %0, %1, %2" : "=v"(w1) : "v"(e2), "v"(e3));
        uint2 w; w.x = w0; w.y = w1;
        *(uint2*)&pl[(qg * 16 + a15) * 72 + sub * 16 + g * 4] = w;
      }
    }
    asm volatile("" ::: "memory");  // order P_lds writes before PV reads
    // --- PV: each V fragment read once, used by both q-groups ---
#pragma unroll
    for (int kc = 0; kc < 2; ++kc) {
      const bf16x8 pa0 = *(const bf16x8*)&pl[a15 * 72 + kc * 32 + g * 8];
      const bf16x8 pa1 = *(const bf16x8*)&pl[(16 + a15) * 72 + kc * 32 + g * 8];
#pragma unroll
      for (int ni = 0; ni < 4; ++ni) {
        const int vrow = ni * 16 + a15;
        const char* vp = (const char*)&V_lds[cur][vrow * 64];
        const int vswz = (vrow & 7) << 4;
        const bf16x8 vb = *(const bf16x8*)(vp + ((kc * 64 + g * 16) ^ vswz));
        acc[0][ni] = __builtin_amdgcn_mfma_f32_16x16x32_bf16(pa0, vb, acc[0][ni], 0, 0, 0);
        acc[1][ni] = __builtin_amdgcn_mfma_f32_16x16x32_bf16(pa1, vb, acc[1][ni], 0, 0, 0);
      }
    }
    __syncthreads();  // drains prefetch (landed under compute) + read/write fence
  }
  // epilogue per q-group
#pragma unroll
  for (int qg = 0; qg < 2; ++qg) {
    float lsum = (ls[qg][0] + ls[qg][1]) + (ls[qg][2] + ls[qg][3]);
    lsum += __shfl_xor(lsum, 16);
    lsum += __shfl_xor(lsum, 32);
    const float li0 = 1.f / (__shfl(lsum, g * 4 + 0) + 1e-30f);
    const float li1 = 1.f / (__shfl(lsum, g * 4 + 1) + 1e-30f);
    const float li2 = 1.f / (__shfl(lsum, g * 4 + 2) + 1e-30f);
    const float li3 = 1.f / (__shfl(lsum, g * 4 + 3) + 1e-30f);
    const int obase = (b * 2048 + qx * 128 + wave * 32 + qg * 16 + g * 4) * 1024 + h * 64 + a15;
#pragma unroll
    for (int ni = 0; ni < 4; ++ni) {
      O[obase + 0 * 1024 + ni * 16] = f2b(acc[qg][ni][0] * li0);
      O[obase + 1 * 1024 + ni * 16] = f2b(acc[qg][ni][1] * li1);
      O[obase + 2 * 1024 + ni * 16] = f2b(acc[qg][ni][2] * li2);
      O[obase + 3 * 1024 + ni * 16] = f2b(acc[qg][ni][3] * li3);
    }
  }
}

extern "C" void kernel_launch(void* const* d_in, const int* in_sizes, int n_in,
                              void* d_out, int out_size, void* d_ws, size_t ws_size,
                              hipStream_t stream) {
  (void)in_sizes; (void)n_in; (void)out_size; (void)ws_size;
  const float* x   = (const float*)d_in[0];
  const float* xo  = (const float*)d_in[1];
  const float* dec = (const float*)d_in[2];
  const float* Wq  = (const float*)d_in[3];
  const float* Wk  = (const float*)d_in[4];
  const float* Wv  = (const float*)d_in[5];
  const float* Wp  = (const float*)d_in[6];
  float* out = (float*)d_out;

  // ws layout (40 MB): Wqt@0(2M) | Wkvt@2M(4M: Wk^T rows 0-1023, Wv^T rows 1024-2047)
  //                    | Wpt@6M(2M) | Qb@8M(16M, becomes O) | Vtb@24M(16M)
  // K parked in d_out (dead until final GEMM overwrites it).
  char* ws = (char*)d_ws;
  u16* Wqt  = (u16*)(ws + ((size_t)0 << 20));
  u16* Wkvt = (u16*)(ws + ((size_t)2 << 20));
  u16* Wpt  = (u16*)(ws + ((size_t)6 << 20));
  u16* Qb   = (u16*)(ws + ((size_t)8 << 20));
  u16* Vtb  = (u16*)(ws + ((size_t)24 << 20));
  u16* Kb   = (u16*)d_out;

  const dim3 blk(256);
  transpose_w4<<<dim3(32, 32, 4), blk, 0, stream>>>(
      Wq, Wk, Wv, Wp, Wqt, Wkvt, Wkvt + 1024 * 1024, Wpt);

  gemm_bt<0, float, u16><<<dim3(64, 8), blk, 0, stream>>>(x, Wqt, Qb, nullptr);
  gemm_bt<2, float, u16><<<dim3(64, 16), blk, 0, stream>>>(xo, Wkvt, Kb, Vtb);

  attn_kernel<<<dim3(1024), blk, 0, stream>>>(Qb, Kb, Vtb, dec, Qb);

  gemm_bt<0, u16, float><<<dim3(64, 8), blk, 0, stream>>>(Qb, Wpt, out, nullptr);
}

// Round 11
// 248.969 us; speedup vs baseline: 2.4693x; 1.0054x over previous
//
#include <hip/hip_runtime.h>

typedef unsigned short u16;
typedef __attribute__((ext_vector_type(8))) short bf16x8;
typedef __attribute__((ext_vector_type(4))) short s16x4;
typedef __attribute__((ext_vector_type(4))) float f32x4;

#define GLDS(g, l) __builtin_amdgcn_global_load_lds( \
    (const __attribute__((address_space(1))) unsigned int*)(g), \
    (__attribute__((address_space(3))) unsigned int*)(l), 16, 0, 0)

__device__ __forceinline__ u16 f2b(float f) {
  unsigned int x = __float_as_uint(f);
  return (u16)((x + 0x7fffu + ((x >> 16) & 1u)) >> 16);
}
__device__ __forceinline__ bf16x8 cvt8(float4 a, float4 b) {
  bf16x8 r;
  r[0] = (short)f2b(a.x); r[1] = (short)f2b(a.y);
  r[2] = (short)f2b(a.z); r[3] = (short)f2b(a.w);
  r[4] = (short)f2b(b.x); r[5] = (short)f2b(b.y);
  r[6] = (short)f2b(b.z); r[7] = (short)f2b(b.w);
  return r;
}

// ---- f32 -> bf16 (RNE) bulk convert: 8 elems/thread ----
// total elements = 8,388,608 -> grid 4096 x 256 threads x 8 elems.
__global__ __launch_bounds__(256) void cvt_f32_bf16(const float* __restrict__ src,
                                                    u16* __restrict__ dst) {
  const int i0 = (blockIdx.x * 256 + threadIdx.x) * 8;
  const float4 a = *(const float4*)&src[i0];
  const float4 b = *(const float4*)&src[i0 + 4];
  *(bf16x8*)&dst[i0] = cvt8(a, b);
}

// ---- all 4 weight transposes in one launch: Wt[n][k] = bf16(W[k][n]) ----
__global__ __launch_bounds__(256) void transpose_w4(
    const float* __restrict__ W0, const float* __restrict__ W1,
    const float* __restrict__ W2, const float* __restrict__ W3,
    u16* __restrict__ D0, u16* __restrict__ D1,
    u16* __restrict__ D2, u16* __restrict__ D3) {
  const int z = blockIdx.z;
  const float* W = (z == 0) ? W0 : (z == 1) ? W1 : (z == 2) ? W2 : W3;
  u16* Wt = (z == 0) ? D0 : (z == 1) ? D1 : (z == 2) ? D2 : D3;
  __shared__ u16 tile[32][33];
  const int tx = threadIdx.x & 31, ty = threadIdx.x >> 5;
  const int r0 = blockIdx.y * 32, c0 = blockIdx.x * 32;
#pragma unroll
  for (int i = 0; i < 32; i += 8)
    tile[ty + i][tx] = f2b(W[(r0 + ty + i) * 1024 + c0 + tx]);
  __syncthreads();
#pragma unroll
  for (int i = 0; i < 32; i += 8)
    Wt[(c0 + ty + i) * 1024 + r0 + tx] = tile[tx][ty + i];
}

// ---------------- C = A(8192x1024) * Bt^T, double-buffered 2-phase ----------------
// A, B: bf16 via global_load_lds width 16 (m97-proven path). 128x128 tile, BK=32,
// 4 waves, 16x16x32 MFMA. Prefetch K-step t+1 during compute(t).
// EPI==0: C row-major (OT u16->bf16 / float->f32).
// EPI==2: fused K|V gemm (Bt has 2048 rows = Wk^T|Wv^T): blockIdx.y<8 -> K row-major
//         into C; y>=8 -> V^T per head into C2: Vt[(b,h),dd,n].
template <int EPI, typename OT>
__global__ __launch_bounds__(256) void gemm_bt(const u16* __restrict__ A,
                                               const u16* __restrict__ Bt,
                                               OT* __restrict__ C,
                                               u16* __restrict__ C2) {
  __shared__ u16 As[2][128 * 32];
  __shared__ u16 Bs[2][128 * 32];
  const int t = threadIdx.x;
  const int wave = t >> 6, lane = t & 63;
  const int g = lane >> 4, a15 = lane & 15;
  const int wr = wave >> 1, wc = wave & 1;
  const int row0 = t >> 2;            // 0..63
  const int col0 = (t & 3) * 8;       // 0,8,16,24
  const int abase = (blockIdx.x * 128 + row0) * 1024 + col0;
  const int bbase = (blockIdx.y * 128 + row0) * 1024 + col0;

  f32x4 acc[4][4] = {};

  // ---- prologue: stage K-step 0 into buffer 0 ----
  GLDS(A + abase, &As[0][wave * 512]);
  GLDS(A + abase + 64 * 1024, &As[0][2048 + wave * 512]);
  GLDS(Bt + bbase, &Bs[0][wave * 512]);
  GLDS(Bt + bbase + 64 * 1024, &Bs[0][2048 + wave * 512]);
  __syncthreads();

  for (int ki = 0; ki < 32; ++ki) {
    const int cur = ki & 1, nxt = cur ^ 1;
    const int ktn = (ki + 1) * 32;
    if (ki < 31) {
      GLDS(A + abase + ktn, &As[nxt][wave * 512]);
      GLDS(A + abase + 64 * 1024 + ktn, &As[nxt][2048 + wave * 512]);
      GLDS(Bt + bbase + ktn, &Bs[nxt][wave * 512]);
      GLDS(Bt + bbase + 64 * 1024 + ktn, &Bs[nxt][2048 + wave * 512]);
    }
    // ---- compute on buffer cur ----
    bf16x8 af[4], bfr[4];
#pragma unroll
    for (int mi = 0; mi < 4; ++mi)
      af[mi] = *(const bf16x8*)&As[cur][(wr * 64 + mi * 16 + a15) * 32 + g * 8];
#pragma unroll
    for (int ni = 0; ni < 4; ++ni)
      bfr[ni] = *(const bf16x8*)&Bs[cur][(wc * 64 + ni * 16 + a15) * 32 + g * 8];
#pragma unroll
    for (int mi = 0; mi < 4; ++mi)
#pragma unroll
      for (int ni = 0; ni < 4; ++ni)
        acc[mi][ni] = __builtin_amdgcn_mfma_f32_16x16x32_bf16(af[mi], bfr[ni], acc[mi][ni], 0, 0, 0);
    __syncthreads();
  }

  const int crow = blockIdx.x * 128 + wr * 64 + g * 4;
  const int ccol = blockIdx.y * 128 + wc * 64 + a15;
  if constexpr (EPI == 0) {
#pragma unroll
    for (int mi = 0; mi < 4; ++mi)
#pragma unroll
      for (int ni = 0; ni < 4; ++ni)
#pragma unroll
        for (int r = 0; r < 4; ++r) {
          const float v = acc[mi][ni][r];
          if constexpr (sizeof(OT) == 2)
            C[(crow + mi * 16 + r) * 1024 + ccol + ni * 16] = (OT)f2b(v);
          else
            C[(crow + mi * 16 + r) * 1024 + ccol + ni * 16] = (OT)v;
        }
  } else {
    if (blockIdx.y < 8) {
      // K part: row-major bf16
#pragma unroll
      for (int mi = 0; mi < 4; ++mi)
#pragma unroll
        for (int ni = 0; ni < 4; ++ni)
#pragma unroll
          for (int r = 0; r < 4; ++r)
            ((u16*)C)[(crow + mi * 16 + r) * 1024 + ccol + ni * 16] = f2b(acc[mi][ni][r]);
    } else {
      // V part: Vt[((b*16+h)*64 + dd)*2048 + n], col c = ccol - 1024
#pragma unroll
      for (int mi = 0; mi < 4; ++mi) {
        const int n = crow + mi * 16;
        const int bq = n >> 11;
        const int nl = n & 2047;
#pragma unroll
        for (int ni = 0; ni < 4; ++ni) {
          const int c = ccol + ni * 16 - 1024;
          s16x4 v4;
          v4[0] = (short)f2b(acc[mi][ni][0]);
          v4[1] = (short)f2b(acc[mi][ni][1]);
          v4[2] = (short)f2b(acc[mi][ni][2]);
          v4[3] = (short)f2b(acc[mi][ni][3]);
          *(s16x4*)&C2[(((bq << 4) + (c >> 6)) * 64 + (c & 63)) * 2048 + nl] = v4;
        }
      }
    }
  }
}

// ---------------- flash attention, fixed-shift log2-domain softmax ----------------
// grid 1024, XCD remap: head bh owned by one XCD -> K/V L2-resident.
// 4 waves/block, QBLK=32 q-rows per wave (128/block), KV step 64, double-buffered
// K/V with prefetch. Each K/V LDS fragment read once, feeds TWO MFMAs (2 q-groups).
// Softmax exact with fixed shift m=0 (shift-invariance; EPS terms <=1e-8).
// O aliases Q (each wave reads exactly the rows it finally overwrites).
__global__ __launch_bounds__(256) void attn_kernel(
    const u16* Q, const u16* __restrict__ K,
    const u16* __restrict__ Vt, const float* __restrict__ dec,
    u16* O) {
  const int f = blockIdx.x;
  const int bh = (f & 7) * 8 + ((f >> 3) & 7);   // 8 heads per XCD
  const int qx = f >> 6;                          // [0,16) q-tile of 128 rows
  const int b = bh >> 4, h = bh & 15;
  __shared__ u16 K_lds[2][64 * 64];  // [key][dim] XOR-swizzled rows, 8KB each
  __shared__ u16 V_lds[2][64 * 64];  // [dd][key] XOR-swizzled rows, 8KB each
  __shared__ __align__(16) u16 P_lds[4][32 * 72];  // per-wave 32 q x 64 keys
  __shared__ float l2p_lds[2048];

  const int wave = threadIdx.x >> 6, lane = threadIdx.x & 63;
  const int g = lane >> 4, a15 = lane & 15;
  u16* pl = &P_lds[wave][0];

  // l2p = log2(1 - dec) computed in-block (8 keys/thread)
  {
    const int i0 = threadIdx.x * 8;
    const float4 d0 = *(const float4*)&dec[b * 2048 + i0];
    const float4 d1 = *(const float4*)&dec[b * 2048 + i0 + 4];
    float4 o0, o1;
    o0.x = __log2f(fmaxf(1.f - d0.x, 1e-38f));
    o0.y = __log2f(fmaxf(1.f - d0.y, 1e-38f));
    o0.z = __log2f(fmaxf(1.f - d0.z, 1e-38f));
    o0.w = __log2f(fmaxf(1.f - d0.w, 1e-38f));
    o1.x = __log2f(fmaxf(1.f - d1.x, 1e-38f));
    o1.y = __log2f(fmaxf(1.f - d1.y, 1e-38f));
    o1.z = __log2f(fmaxf(1.f - d1.z, 1e-38f));
    o1.w = __log2f(fmaxf(1.f - d1.w, 1e-38f));
    *(float4*)&l2p_lds[i0] = o0;
    *(float4*)&l2p_lds[i0 + 4] = o1;
  }

  // Q fragments for two 16-row groups (rows qx*128 + wave*32 + qg*16 + a15)
  bf16x8 qf[2][2];
  {
    const int qr = (b * 2048 + qx * 128 + wave * 32 + a15) * 1024 + h * 64 + g * 8;
#pragma unroll
    for (int qg = 0; qg < 2; ++qg) {
      qf[qg][0] = *(const bf16x8*)&Q[qr + qg * 16 * 1024];
      qf[qg][1] = *(const bf16x8*)&Q[qr + qg * 16 * 1024 + 32];
    }
  }

  // staging mapping: row-in-8 = lane>>3, colByte = (lane&7)*16; tile rows step
  // by 8 per GLDS so (row&7)==(lane>>3): source swizzle is a per-lane constant.
  const int srow = lane >> 3;
  const int swze = (((lane & 7) * 16) ^ (srow << 4)) >> 1;  // u16 elems
  const u16* Kg = K + ((size_t)(b * 2048 + wave * 16 + srow)) * 1024 + h * 64 + swze;
  const u16* Vg = Vt + ((size_t)(bh * 64 + wave * 16 + srow)) * 2048 + swze;

  // ---- prologue: stage tile 0 into buffer 0 ----
  GLDS(Kg, &K_lds[0][(wave * 16 + 0) * 64]);
  GLDS(Kg + (size_t)8 * 1024, &K_lds[0][(wave * 16 + 8) * 64]);
  GLDS(Vg, &V_lds[0][(wave * 16 + 0) * 64]);
  GLDS(Vg + 8 * 2048, &V_lds[0][(wave * 16 + 8) * 64]);
  __syncthreads();

  const float CSC = 0.125f * 1.44269504f;  // scale * log2(e)
  f32x4 acc[2][4] = {};
  f32x4 ls[2] = {};

  for (int it = 0; it < 32; ++it) {
    const int cur = it & 1, nxt = cur ^ 1;
    if (it < 31) {
      const int ktn = (it + 1) * 64;
      GLDS(Kg + (size_t)ktn * 1024, &K_lds[nxt][(wave * 16 + 0) * 64]);
      GLDS(Kg + (size_t)(ktn + 8) * 1024, &K_lds[nxt][(wave * 16 + 8) * 64]);
      GLDS(Vg + ktn, &V_lds[nxt][(wave * 16 + 0) * 64]);
      GLDS(Vg + ktn + 8 * 2048, &V_lds[nxt][(wave * 16 + 8) * 64]);
    }
    const int kt = it * 64;
    // --- S^T = K * Q^T : each K fragment read once, used by both q-groups ---
    f32x4 sf[2][4];
#pragma unroll
    for (int sub = 0; sub < 4; ++sub) {
      const int krow = sub * 16 + a15;
      const char* kp = (const char*)&K_lds[cur][krow * 64];
      const int swz = (krow & 7) << 4;
      const bf16x8 k0 = *(const bf16x8*)(kp + ((g * 16) ^ swz));
      const bf16x8 k1 = *(const bf16x8*)(kp + ((g * 16 + 64) ^ swz));
#pragma unroll
      for (int qg = 0; qg < 2; ++qg) {
        f32x4 s = {0.f, 0.f, 0.f, 0.f};
        s = __builtin_amdgcn_mfma_f32_16x16x32_bf16(k0, qf[qg][0], s, 0, 0, 0);
        s = __builtin_amdgcn_mfma_f32_16x16x32_bf16(k1, qf[qg][1], s, 0, 0, 0);
        sf[qg][sub] = s;
      }
    }
    // --- straight-line softmax both groups: e = exp2(s*CSC + l2p) ---
#pragma unroll
    for (int qg = 0; qg < 2; ++qg) {
#pragma unroll
      for (int sub = 0; sub < 4; ++sub) {
        const float4 lp = *(const float4*)&l2p_lds[kt + sub * 16 + g * 4];
        const float e0 = __builtin_amdgcn_exp2f(fmaf(sf[qg][sub][0], CSC, lp.x));
        const float e1 = __builtin_amdgcn_exp2f(fmaf(sf[qg][sub][1], CSC, lp.y));
        const float e2 = __builtin_amdgcn_exp2f(fmaf(sf[qg][sub][2], CSC, lp.z));
        const float e3 = __builtin_amdgcn_exp2f(fmaf(sf[qg][sub][3], CSC, lp.w));
        ls[qg][0] += e0; ls[qg][1] += e1; ls[qg][2] += e2; ls[qg][3] += e3;
        unsigned int w0, w1;
        asm("v_cvt_pk_bf16_f32 %0, %1, %2" : "=v"(w0) : "v"(e0), "v"(e1));
        asm("v_cvt_pk_bf16_f32 %0, %1, %2" : "=v"(w1) : "v"(e2), "v"(e3));
        uint2 w; w.x = w0; w.y = w1;
        *(uint2*)&pl[(qg * 16 + a15) * 72 + sub * 16 + g * 4] = w;
      }
    }
    asm volatile("" ::: "memory");  // order P_lds writes before PV reads
    // --- PV: each V fragment read once, used by both q-groups ---
#pragma unroll
    for (int kc = 0; kc < 2; ++kc) {
      const bf16x8 pa0 = *(const bf16x8*)&pl[a15 * 72 + kc * 32 + g * 8];
      const bf16x8 pa1 = *(const bf16x8*)&pl[(16 + a15) * 72 + kc * 32 + g * 8];
#pragma unroll
      for (int ni = 0; ni < 4; ++ni) {
        const int vrow = ni * 16 + a15;
        const char* vp = (const char*)&V_lds[cur][vrow * 64];
        const int vswz = (vrow & 7) << 4;
        const bf16x8 vb = *(const bf16x8*)(vp + ((kc * 64 + g * 16) ^ vswz));
        acc[0][ni] = __builtin_amdgcn_mfma_f32_16x16x32_bf16(pa0, vb, acc[0][ni], 0, 0, 0);
        acc[1][ni] = __builtin_amdgcn_mfma_f32_16x16x32_bf16(pa1, vb, acc[1][ni], 0, 0, 0);
      }
    }
    __syncthreads();  // drains prefetch (landed under compute) + read/write fence
  }
  // epilogue per q-group
#pragma unroll
  for (int qg = 0; qg < 2; ++qg) {
    float lsum = (ls[qg][0] + ls[qg][1]) + (ls[qg][2] + ls[qg][3]);
    lsum += __shfl_xor(lsum, 16);
    lsum += __shfl_xor(lsum, 32);
    const float li0 = 1.f / (__shfl(lsum, g * 4 + 0) + 1e-30f);
    const float li1 = 1.f / (__shfl(lsum, g * 4 + 1) + 1e-30f);
    const float li2 = 1.f / (__shfl(lsum, g * 4 + 2) + 1e-30f);
    const float li3 = 1.f / (__shfl(lsum, g * 4 + 3) + 1e-30f);
    const int obase = (b * 2048 + qx * 128 + wave * 32 + qg * 16 + g * 4) * 1024 + h * 64 + a15;
#pragma unroll
    for (int ni = 0; ni < 4; ++ni) {
      O[obase + 0 * 1024 + ni * 16] = f2b(acc[qg][ni][0] * li0);
      O[obase + 1 * 1024 + ni * 16] = f2b(acc[qg][ni][1] * li1);
      O[obase + 2 * 1024 + ni * 16] = f2b(acc[qg][ni][2] * li2);
      O[obase + 3 * 1024 + ni * 16] = f2b(acc[qg][ni][3] * li3);
    }
  }
}

extern "C" void kernel_launch(void* const* d_in, const int* in_sizes, int n_in,
                              void* d_out, int out_size, void* d_ws, size_t ws_size,
                              hipStream_t stream) {
  (void)in_sizes; (void)n_in; (void)out_size; (void)ws_size;
  const float* x   = (const float*)d_in[0];
  const float* xo  = (const float*)d_in[1];
  const float* dec = (const float*)d_in[2];
  const float* Wq  = (const float*)d_in[3];
  const float* Wk  = (const float*)d_in[4];
  const float* Wv  = (const float*)d_in[5];
  const float* Wp  = (const float*)d_in[6];
  float* out = (float*)d_out;

  // ws (40 MB, validated): Wqt@0(2M) | Wkvt@2M(4M) | Wpt@6M(2M) | Qb@8M(16M,
  // becomes O) | Vtb@24M(16M).
  // d_out (32 MiB) scratch use before final overwrite: Kb@0 (16MiB bf16 K),
  // Xb@16MiB (16MiB bf16 converted activations; xo then x, sequentially).
  char* ws = (char*)d_ws;
  u16* Wqt  = (u16*)(ws + ((size_t)0 << 20));
  u16* Wkvt = (u16*)(ws + ((size_t)2 << 20));
  u16* Wpt  = (u16*)(ws + ((size_t)6 << 20));
  u16* Qb   = (u16*)(ws + ((size_t)8 << 20));
  u16* Vtb  = (u16*)(ws + ((size_t)24 << 20));
  u16* Kb   = (u16*)d_out;
  u16* Xb   = (u16*)((char*)d_out + ((size_t)16 << 20));

  const dim3 blk(256);
  transpose_w4<<<dim3(32, 32, 4), blk, 0, stream>>>(
      Wq, Wk, Wv, Wp, Wqt, Wkvt, Wkvt + 1024 * 1024, Wpt);

  cvt_f32_bf16<<<dim3(4096), blk, 0, stream>>>(xo, Xb);
  gemm_bt<2, u16><<<dim3(64, 16), blk, 0, stream>>>(Xb, Wkvt, Kb, Vtb);

  cvt_f32_bf16<<<dim3(4096), blk, 0, stream>>>(x, Xb);
  gemm_bt<0, u16><<<dim3(64, 8), blk, 0, stream>>>(Xb, Wqt, Qb, nullptr);

  attn_kernel<<<dim3(1024), blk, 0, stream>>>(Qb, Kb, Vtb, dec, Qb);

  gemm_bt<0, float><<<dim3(64, 8), blk, 0, stream>>>(Qb, Wpt, out, nullptr);
}

// Round 13
// 223.188 us; speedup vs baseline: 2.7545x; 1.1155x over previous
//
#include <hip/hip_runtime.h>

typedef unsigned short u16;
typedef __attribute__((ext_vector_type(8))) short bf16x8;
typedef __attribute__((ext_vector_type(4))) short s16x4;
typedef __attribute__((ext_vector_type(4))) float f32x4;

#define GLDS(g, l) __builtin_amdgcn_global_load_lds( \
    (const __attribute__((address_space(1))) unsigned int*)(g), \
    (__attribute__((address_space(3))) unsigned int*)(l), 16, 0, 0)

__device__ __forceinline__ u16 f2b(float f) {
  unsigned int x = __float_as_uint(f);
  return (u16)((x + 0x7fffu + ((x >> 16) & 1u)) >> 16);
}
__device__ __forceinline__ bf16x8 cvt8(float4 a, float4 b) {
  bf16x8 r;
  r[0] = (short)f2b(a.x); r[1] = (short)f2b(a.y);
  r[2] = (short)f2b(a.z); r[3] = (short)f2b(a.w);
  r[4] = (short)f2b(b.x); r[5] = (short)f2b(b.y);
  r[6] = (short)f2b(b.z); r[7] = (short)f2b(b.w);
  return r;
}

// ---- f32 -> bf16 (RNE) bulk convert: 8,388,608 elems -> grid 4096 ----
__global__ __launch_bounds__(256) void cvt_f32_bf16(const float* __restrict__ src,
                                                    u16* __restrict__ dst) {
  const int i0 = (blockIdx.x * 256 + threadIdx.x) * 8;
  const float4 a = *(const float4*)&src[i0];
  const float4 b = *(const float4*)&src[i0 + 4];
  *(bf16x8*)&dst[i0] = cvt8(a, b);
}

// ---- all 4 weight transposes in one launch: Wt[n][k] = bf16(W[k][n]) ----
__global__ __launch_bounds__(256) void transpose_w4(
    const float* __restrict__ W0, const float* __restrict__ W1,
    const float* __restrict__ W2, const float* __restrict__ W3,
    u16* __restrict__ D0, u16* __restrict__ D1,
    u16* __restrict__ D2, u16* __restrict__ D3) {
  const int z = blockIdx.z;
  const float* W = (z == 0) ? W0 : (z == 1) ? W1 : (z == 2) ? W2 : W3;
  u16* Wt = (z == 0) ? D0 : (z == 1) ? D1 : (z == 2) ? D2 : D3;
  __shared__ u16 tile[32][33];
  const int tx = threadIdx.x & 31, ty = threadIdx.x >> 5;
  const int r0 = blockIdx.y * 32, c0 = blockIdx.x * 32;
#pragma unroll
  for (int i = 0; i < 32; i += 8)
    tile[ty + i][tx] = f2b(W[(r0 + ty + i) * 1024 + c0 + tx]);
  __syncthreads();
#pragma unroll
  for (int i = 0; i < 32; i += 8)
    Wt[(c0 + ty + i) * 1024 + r0 + tx] = tile[tx][ty + i];
}

// ---------------- C = A(8192x1024) * Bt^T, double-buffered 2-phase ----------------
// A, B: bf16 via global_load_lds width 16. 128x128 tile, BK=32, 4 waves,
// 16x16x32 MFMA. Prefetch K-step t+1 during compute(t).
// EPI==0: C row-major (OT u16->bf16 / float->f32).
// EPI==2: fused K|V gemm (Bt has 2048 rows = Wk^T|Wv^T): blockIdx.y<8 -> K row-major
//         into C; y>=8 -> V^T per head into C2: Vt[(b,h),dd,n].
template <int EPI, typename OT>
__global__ __launch_bounds__(256) void gemm_bt(const u16* __restrict__ A,
                                               const u16* __restrict__ Bt,
                                               OT* __restrict__ C,
                                               u16* __restrict__ C2) {
  __shared__ u16 As[2][128 * 32];
  __shared__ u16 Bs[2][128 * 32];
  const int t = threadIdx.x;
  const int wave = t >> 6, lane = t & 63;
  const int g = lane >> 4, a15 = lane & 15;
  const int wr = wave >> 1, wc = wave & 1;
  const int row0 = t >> 2;            // 0..63
  const int col0 = (t & 3) * 8;       // 0,8,16,24
  const int abase = (blockIdx.x * 128 + row0) * 1024 + col0;
  const int bbase = (blockIdx.y * 128 + row0) * 1024 + col0;

  f32x4 acc[4][4] = {};

  GLDS(A + abase, &As[0][wave * 512]);
  GLDS(A + abase + 64 * 1024, &As[0][2048 + wave * 512]);
  GLDS(Bt + bbase, &Bs[0][wave * 512]);
  GLDS(Bt + bbase + 64 * 1024, &Bs[0][2048 + wave * 512]);
  __syncthreads();

  for (int ki = 0; ki < 32; ++ki) {
    const int cur = ki & 1, nxt = cur ^ 1;
    const int ktn = (ki + 1) * 32;
    if (ki < 31) {
      GLDS(A + abase + ktn, &As[nxt][wave * 512]);
      GLDS(A + abase + 64 * 1024 + ktn, &As[nxt][2048 + wave * 512]);
      GLDS(Bt + bbase + ktn, &Bs[nxt][wave * 512]);
      GLDS(Bt + bbase + 64 * 1024 + ktn, &Bs[nxt][2048 + wave * 512]);
    }
    bf16x8 af[4], bfr[4];
#pragma unroll
    for (int mi = 0; mi < 4; ++mi)
      af[mi] = *(const bf16x8*)&As[cur][(wr * 64 + mi * 16 + a15) * 32 + g * 8];
#pragma unroll
    for (int ni = 0; ni < 4; ++ni)
      bfr[ni] = *(const bf16x8*)&Bs[cur][(wc * 64 + ni * 16 + a15) * 32 + g * 8];
#pragma unroll
    for (int mi = 0; mi < 4; ++mi)
#pragma unroll
      for (int ni = 0; ni < 4; ++ni)
        acc[mi][ni] = __builtin_amdgcn_mfma_f32_16x16x32_bf16(af[mi], bfr[ni], acc[mi][ni], 0, 0, 0);
    __syncthreads();
  }

  const int crow = blockIdx.x * 128 + wr * 64 + g * 4;
  const int ccol = blockIdx.y * 128 + wc * 64 + a15;
  if constexpr (EPI == 0) {
#pragma unroll
    for (int mi = 0; mi < 4; ++mi)
#pragma unroll
      for (int ni = 0; ni < 4; ++ni)
#pragma unroll
        for (int r = 0; r < 4; ++r) {
          const float v = acc[mi][ni][r];
          if constexpr (sizeof(OT) == 2)
            C[(crow + mi * 16 + r) * 1024 + ccol + ni * 16] = (OT)f2b(v);
          else
            C[(crow + mi * 16 + r) * 1024 + ccol + ni * 16] = (OT)v;
        }
  } else {
    if (blockIdx.y < 8) {
#pragma unroll
      for (int mi = 0; mi < 4; ++mi)
#pragma unroll
        for (int ni = 0; ni < 4; ++ni)
#pragma unroll
          for (int r = 0; r < 4; ++r)
            ((u16*)C)[(crow + mi * 16 + r) * 1024 + ccol + ni * 16] = f2b(acc[mi][ni][r]);
    } else {
#pragma unroll
      for (int mi = 0; mi < 4; ++mi) {
        const int n = crow + mi * 16;
        const int bq = n >> 11;
        const int nl = n & 2047;
#pragma unroll
        for (int ni = 0; ni < 4; ++ni) {
          const int c = ccol + ni * 16 - 1024;
          s16x4 v4;
          v4[0] = (short)f2b(acc[mi][ni][0]);
          v4[1] = (short)f2b(acc[mi][ni][1]);
          v4[2] = (short)f2b(acc[mi][ni][2]);
          v4[3] = (short)f2b(acc[mi][ni][3]);
          *(s16x4*)&C2[(((bq << 4) + (c >> 6)) * 64 + (c & 63)) * 2048 + nl] = v4;
        }
      }
    }
  }
}

// ---------------- flash attention, fixed-shift log2-domain softmax ----------------
// 512-thread blocks (8 waves) sharing one K/V tile; grid 512 = exactly 2 blocks/CU
// (16 waves/CU, 4/SIMD -- 2x r11). Semantics byte-identical to the r11-passing
// kernel: l2p in LDS, same staging swizzle, same P round-trip, same math.
// Each wave owns 32 q-rows (block: 256 rows x one head). KV step 64, double-
// buffered with prefetch; each K/V LDS fragment read once, feeds 2 q-group MFMAs.
// Softmax exact with fixed shift m=0 (shift-invariance; EPS terms <=1e-8).
// O aliases Q (each wave reads exactly the rows it finally overwrites).
__global__ __launch_bounds__(512) void attn_kernel(
    const u16* Q, const u16* __restrict__ K,
    const u16* __restrict__ Vt, const float* __restrict__ dec,
    u16* O) {
  const int f = blockIdx.x;
  const int bh = (f & 7) * 8 + ((f >> 3) & 7);   // 8 heads per XCD
  const int qx = f >> 6;                          // [0,8) q-tile of 256 rows
  const int b = bh >> 4, h = bh & 15;
  __shared__ u16 K_lds[2][64 * 64];  // [key][dim] XOR-swizzled rows, 8KB each
  __shared__ u16 V_lds[2][64 * 64];  // [dd][key] XOR-swizzled rows, 8KB each
  __shared__ __align__(16) u16 P_lds[8][32 * 72];  // per-wave 32 q x 64 keys
  __shared__ float l2p_lds[2048];

  const int wave = threadIdx.x >> 6, lane = threadIdx.x & 63;
  const int g = lane >> 4, a15 = lane & 15;
  u16* pl = &P_lds[wave][0];

  // l2p = log2(1 - dec) computed in-block (4 keys/thread, 512 threads)
  {
    const int i0 = threadIdx.x * 4;
    const float4 d0 = *(const float4*)&dec[b * 2048 + i0];
    float4 o0;
    o0.x = __log2f(fmaxf(1.f - d0.x, 1e-38f));
    o0.y = __log2f(fmaxf(1.f - d0.y, 1e-38f));
    o0.z = __log2f(fmaxf(1.f - d0.z, 1e-38f));
    o0.w = __log2f(fmaxf(1.f - d0.w, 1e-38f));
    *(float4*)&l2p_lds[i0] = o0;
  }

  // Q fragments for two 16-row groups (rows qx*256 + wave*32 + qg*16 + a15)
  bf16x8 qf[2][2];
  {
    const int qr = (b * 2048 + qx * 256 + wave * 32 + a15) * 1024 + h * 64 + g * 8;
#pragma unroll
    for (int qg = 0; qg < 2; ++qg) {
      qf[qg][0] = *(const bf16x8*)&Q[qr + qg * 16 * 1024];
      qf[qg][1] = *(const bf16x8*)&Q[qr + qg * 16 * 1024 + 32];
    }
  }

  // staging: each wave stages 8 rows of K and 8 of V per tile (1 GLDS each).
  // row-in-8 = lane>>3, colByte = (lane&7)*16; wave's rows = wave*8..+8 so
  // (tile_row & 7) == (lane>>3): source swizzle is a per-lane constant.
  const int srow = lane >> 3;
  const int swze = (((lane & 7) * 16) ^ (srow << 4)) >> 1;  // u16 elems
  const u16* Kg = K + ((size_t)(b * 2048 + wave * 8 + srow)) * 1024 + h * 64 + swze;
  const u16* Vg = Vt + ((size_t)(bh * 64 + wave * 8 + srow)) * 2048 + swze;
  u16* kdst[2] = {&K_lds[0][wave * 8 * 64], &K_lds[1][wave * 8 * 64]};
  u16* vdst[2] = {&V_lds[0][wave * 8 * 64], &V_lds[1][wave * 8 * 64]};

  // ---- prologue: stage tile 0 into buffer 0 ----
  GLDS(Kg, kdst[0]);
  GLDS(Vg, vdst[0]);
  __syncthreads();

  const float CSC = 0.125f * 1.44269504f;  // scale * log2(e)
  f32x4 acc[2][4] = {};
  f32x4 ls[2] = {};

  for (int it = 0; it < 32; ++it) {
    const int cur = it & 1, nxt = cur ^ 1;
    if (it < 31) {
      const int ktn = (it + 1) * 64;
      GLDS(Kg + (size_t)ktn * 1024, kdst[nxt]);
      GLDS(Vg + ktn, vdst[nxt]);
    }
    const int kt = it * 64;
    // --- S^T = K * Q^T : each K fragment read once, used by both q-groups ---
    f32x4 sf[2][4];
#pragma unroll
    for (int sub = 0; sub < 4; ++sub) {
      const int krow = sub * 16 + a15;
      const char* kp = (const char*)&K_lds[cur][krow * 64];
      const int swz = (krow & 7) << 4;
      const bf16x8 k0 = *(const bf16x8*)(kp + ((g * 16) ^ swz));
      const bf16x8 k1 = *(const bf16x8*)(kp + ((g * 16 + 64) ^ swz));
#pragma unroll
      for (int qg = 0; qg < 2; ++qg) {
        f32x4 s = {0.f, 0.f, 0.f, 0.f};
        s = __builtin_amdgcn_mfma_f32_16x16x32_bf16(k0, qf[qg][0], s, 0, 0, 0);
        s = __builtin_amdgcn_mfma_f32_16x16x32_bf16(k1, qf[qg][1], s, 0, 0, 0);
        sf[qg][sub] = s;
      }
    }
    // --- straight-line softmax both groups: e = exp2(s*CSC + l2p) ---
#pragma unroll
    for (int qg = 0; qg < 2; ++qg) {
#pragma unroll
      for (int sub = 0; sub < 4; ++sub) {
        const float4 lp = *(const float4*)&l2p_lds[kt + sub * 16 + g * 4];
        const float e0 = __builtin_amdgcn_exp2f(fmaf(sf[qg][sub][0], CSC, lp.x));
        const float e1 = __builtin_amdgcn_exp2f(fmaf(sf[qg][sub][1], CSC, lp.y));
        const float e2 = __builtin_amdgcn_exp2f(fmaf(sf[qg][sub][2], CSC, lp.z));
        const float e3 = __builtin_amdgcn_exp2f(fmaf(sf[qg][sub][3], CSC, lp.w));
        ls[qg][0] += e0; ls[qg][1] += e1; ls[qg][2] += e2; ls[qg][3] += e3;
        unsigned int w0, w1;
        asm("v_cvt_pk_bf16_f32 %0, %1, %2" : "=v"(w0) : "v"(e0), "v"(e1));
        asm("v_cvt_pk_bf16_f32 %0, %1, %2" : "=v"(w1) : "v"(e2), "v"(e3));
        uint2 w; w.x = w0; w.y = w1;
        *(uint2*)&pl[(qg * 16 + a15) * 72 + sub * 16 + g * 4] = w;
      }
    }
    asm volatile("" ::: "memory");  // order P_lds writes before PV reads
    // --- PV: each V fragment read once, used by both q-groups ---
#pragma unroll
    for (int kc = 0; kc < 2; ++kc) {
      const bf16x8 pa0 = *(const bf16x8*)&pl[a15 * 72 + kc * 32 + g * 8];
      const bf16x8 pa1 = *(const bf16x8*)&pl[(16 + a15) * 72 + kc * 32 + g * 8];
#pragma unroll
      for (int ni = 0; ni < 4; ++ni) {
        const int vrow = ni * 16 + a15;
        const char* vp = (const char*)&V_lds[cur][vrow * 64];
        const int vswz = (vrow & 7) << 4;
        const bf16x8 vb = *(const bf16x8*)(vp + ((kc * 64 + g * 16) ^ vswz));
        acc[0][ni] = __builtin_amdgcn_mfma_f32_16x16x32_bf16(pa0, vb, acc[0][ni], 0, 0, 0);
        acc[1][ni] = __builtin_amdgcn_mfma_f32_16x16x32_bf16(pa1, vb, acc[1][ni], 0, 0, 0);
      }
    }
    __syncthreads();  // drains prefetch (landed under compute) + read/write fence
  }
  // epilogue per q-group
#pragma unroll
  for (int qg = 0; qg < 2; ++qg) {
    float lsum = (ls[qg][0] + ls[qg][1]) + (ls[qg][2] + ls[qg][3]);
    lsum += __shfl_xor(lsum, 16);
    lsum += __shfl_xor(lsum, 32);
    const float li0 = 1.f / (__shfl(lsum, g * 4 + 0) + 1e-30f);
    const float li1 = 1.f / (__shfl(lsum, g * 4 + 1) + 1e-30f);
    const float li2 = 1.f / (__shfl(lsum, g * 4 + 2) + 1e-30f);
    const float li3 = 1.f / (__shfl(lsum, g * 4 + 3) + 1e-30f);
    const int obase = (b * 2048 + qx * 256 + wave * 32 + qg * 16 + g * 4) * 1024 + h * 64 + a15;
#pragma unroll
    for (int ni = 0; ni < 4; ++ni) {
      O[obase + 0 * 1024 + ni * 16] = f2b(acc[qg][ni][0] * li0);
      O[obase + 1 * 1024 + ni * 16] = f2b(acc[qg][ni][1] * li1);
      O[obase + 2 * 1024 + ni * 16] = f2b(acc[qg][ni][2] * li2);
      O[obase + 3 * 1024 + ni * 16] = f2b(acc[qg][ni][3] * li3);
    }
  }
}

extern "C" void kernel_launch(void* const* d_in, const int* in_sizes, int n_in,
                              void* d_out, int out_size, void* d_ws, size_t ws_size,
                              hipStream_t stream) {
  (void)in_sizes; (void)n_in; (void)out_size; (void)ws_size;
  const float* x   = (const float*)d_in[0];
  const float* xo  = (const float*)d_in[1];
  const float* dec = (const float*)d_in[2];
  const float* Wq  = (const float*)d_in[3];
  const float* Wk  = (const float*)d_in[4];
  const float* Wv  = (const float*)d_in[5];
  const float* Wp  = (const float*)d_in[6];
  float* out = (float*)d_out;

  // ws (40 MB): Wqt@0(2M) | Wkvt@2M(4M) | Wpt@6M(2M) | Qb@8M(16M, becomes O) |
  //   Vtb@24M(16M).
  // d_out (32 MiB) scratch before final overwrite: Kb@0 (16MiB bf16 K),
  // Xb@16MiB (16MiB bf16 converted activations; xo then x, sequentially).
  char* ws = (char*)d_ws;
  u16* Wqt  = (u16*)(ws + ((size_t)0 << 20));
  u16* Wkvt = (u16*)(ws + ((size_t)2 << 20));
  u16* Wpt  = (u16*)(ws + ((size_t)6 << 20));
  u16* Qb   = (u16*)(ws + ((size_t)8 << 20));
  u16* Vtb  = (u16*)(ws + ((size_t)24 << 20));
  u16* Kb   = (u16*)d_out;
  u16* Xb   = (u16*)((char*)d_out + ((size_t)16 << 20));

  const dim3 blk(256);
  transpose_w4<<<dim3(32, 32, 4), blk, 0, stream>>>(
      Wq, Wk, Wv, Wp, Wqt, Wkvt, Wkvt + 1024 * 1024, Wpt);

  cvt_f32_bf16<<<dim3(4096), blk, 0, stream>>>(xo, Xb);
  gemm_bt<2, u16><<<dim3(64, 16), blk, 0, stream>>>(Xb, Wkvt, Kb, Vtb);

  cvt_f32_bf16<<<dim3(4096), blk, 0, stream>>>(x, Xb);
  gemm_bt<0, u16><<<dim3(64, 8), blk, 0, stream>>>(Xb, Wqt, Qb, nullptr);

  attn_kernel<<<dim3(512), dim3(512), 0, stream>>>(Qb, Kb, Vtb, dec, Qb);

  gemm_bt<0, float><<<dim3(64, 8), blk, 0, stream>>>(Qb, Wpt, out, nullptr);
}

// Round 14
// 199.258 us; speedup vs baseline: 3.0853x; 1.1201x over previous
//
#include <hip/hip_runtime.h>

typedef unsigned short u16;
typedef __attribute__((ext_vector_type(8))) short bf16x8;
typedef __attribute__((ext_vector_type(4))) short s16x4;
typedef __attribute__((ext_vector_type(4))) float f32x4;

#define GLDS(g, l) __builtin_amdgcn_global_load_lds( \
    (const __attribute__((address_space(1))) unsigned int*)(g), \
    (__attribute__((address_space(3))) unsigned int*)(l), 16, 0, 0)

__device__ __forceinline__ u16 f2b(float f) {
  unsigned int x = __float_as_uint(f);
  return (u16)((x + 0x7fffu + ((x >> 16) & 1u)) >> 16);
}
__device__ __forceinline__ bf16x8 cvt8(float4 a, float4 b) {
  bf16x8 r;
  r[0] = (short)f2b(a.x); r[1] = (short)f2b(a.y);
  r[2] = (short)f2b(a.z); r[3] = (short)f2b(a.w);
  r[4] = (short)f2b(b.x); r[5] = (short)f2b(b.y);
  r[6] = (short)f2b(b.z); r[7] = (short)f2b(b.w);
  return r;
}

// ---- f32 -> bf16 (RNE) bulk convert: 8,388,608 elems -> grid 4096 ----
__global__ __launch_bounds__(256) void cvt_f32_bf16(const float* __restrict__ src,
                                                    u16* __restrict__ dst) {
  const int i0 = (blockIdx.x * 256 + threadIdx.x) * 8;
  const float4 a = *(const float4*)&src[i0];
  const float4 b = *(const float4*)&src[i0 + 4];
  *(bf16x8*)&dst[i0] = cvt8(a, b);
}

// ---- all 4 weight transposes in one launch: Wt[n][k] = bf16(W[k][n]) ----
__global__ __launch_bounds__(256) void transpose_w4(
    const float* __restrict__ W0, const float* __restrict__ W1,
    const float* __restrict__ W2, const float* __restrict__ W3,
    u16* __restrict__ D0, u16* __restrict__ D1,
    u16* __restrict__ D2, u16* __restrict__ D3) {
  const int z = blockIdx.z;
  const float* W = (z == 0) ? W0 : (z == 1) ? W1 : (z == 2) ? W2 : W3;
  u16* Wt = (z == 0) ? D0 : (z == 1) ? D1 : (z == 2) ? D2 : D3;
  __shared__ u16 tile[32][33];
  const int tx = threadIdx.x & 31, ty = threadIdx.x >> 5;
  const int r0 = blockIdx.y * 32, c0 = blockIdx.x * 32;
#pragma unroll
  for (int i = 0; i < 32; i += 8)
    tile[ty + i][tx] = f2b(W[(r0 + ty + i) * 1024 + c0 + tx]);
  __syncthreads();
#pragma unroll
  for (int i = 0; i < 32; i += 8)
    Wt[(c0 + ty + i) * 1024 + r0 + tx] = tile[tx][ty + i];
}

// ------- FUSED Q + K + V projection GEMM: one launch, grid (64, 24) -------
// y<8:    Q-part:  A = x (f32, reg-staged->bf16 LDS, RNE == cvt kernel),
//                  Bt = Wqt, C = Qb row-major bf16, ccol = y*128.
// y in [8,24): KV-part: A = Xb (xo bf16, global_load_lds), Bt = Wkvt rows
//                  (y-8)*128; y-8<8 -> K row-major; else V^T scatter to Vtb.
// 128x128 tile, BK=32, 4 waves, 16x16x32 MFMA, double-buffered prefetch.
__global__ __launch_bounds__(256) void gemm_fused(
    const float* __restrict__ Ax, const u16* __restrict__ Axo,
    const u16* __restrict__ Wqt, const u16* __restrict__ Wkvt,
    u16* __restrict__ Qb, u16* __restrict__ Kb, u16* __restrict__ Vtb) {
  __shared__ u16 As[2][128 * 32];
  __shared__ u16 Bs[2][128 * 32];
  const int t = threadIdx.x;
  const int wave = t >> 6, lane = t & 63;
  const int g = lane >> 4, a15 = lane & 15;
  const int wr = wave >> 1, wc = wave & 1;
  const int row0 = t >> 2;            // 0..63
  const int col0 = (t & 3) * 8;       // 0,8,16,24
  const int y = blockIdx.y;
  const bool qpart = (y < 8);
  const u16* Bt = qpart ? Wqt : Wkvt;
  const int yb = qpart ? y : (y - 8);
  const int abase = (blockIdx.x * 128 + row0) * 1024 + col0;
  const int bbase = (yb * 128 + row0) * 1024 + col0;

  f32x4 acc[4][4] = {};

  // ---- prologue: stage K-step 0 into buffer 0 ----
  GLDS(Bt + bbase, &Bs[0][wave * 512]);
  GLDS(Bt + bbase + 64 * 1024, &Bs[0][2048 + wave * 512]);
  if (qpart) {
    const float* Ag = Ax + abase;
    const float4 x0 = *(const float4*)(Ag);
    const float4 x1 = *(const float4*)(Ag + 4);
    const float4 y0 = *(const float4*)(Ag + 64 * 1024);
    const float4 y1 = *(const float4*)(Ag + 64 * 1024 + 4);
    *(bf16x8*)&As[0][row0 * 32 + col0] = cvt8(x0, x1);
    *(bf16x8*)&As[0][(row0 + 64) * 32 + col0] = cvt8(y0, y1);
  } else {
    GLDS(Axo + abase, &As[0][wave * 512]);
    GLDS(Axo + abase + 64 * 1024, &As[0][2048 + wave * 512]);
  }
  __syncthreads();

  for (int ki = 0; ki < 32; ++ki) {
    const int cur = ki & 1, nxt = cur ^ 1;
    const int ktn = (ki + 1) * 32;
    const bool pf = ki < 31;
    float4 x0, x1, y0, y1;
    if (pf) {
      GLDS(Bt + bbase + ktn, &Bs[nxt][wave * 512]);
      GLDS(Bt + bbase + 64 * 1024 + ktn, &Bs[nxt][2048 + wave * 512]);
      if (qpart) {
        const float* Ag = Ax + abase + ktn;
        x0 = *(const float4*)(Ag);
        x1 = *(const float4*)(Ag + 4);
        y0 = *(const float4*)(Ag + 64 * 1024);
        y1 = *(const float4*)(Ag + 64 * 1024 + 4);
      } else {
        GLDS(Axo + abase + ktn, &As[nxt][wave * 512]);
        GLDS(Axo + abase + 64 * 1024 + ktn, &As[nxt][2048 + wave * 512]);
      }
    }
    bf16x8 af[4], bfr[4];
#pragma unroll
    for (int mi = 0; mi < 4; ++mi)
      af[mi] = *(const bf16x8*)&As[cur][(wr * 64 + mi * 16 + a15) * 32 + g * 8];
#pragma unroll
    for (int ni = 0; ni < 4; ++ni)
      bfr[ni] = *(const bf16x8*)&Bs[cur][(wc * 64 + ni * 16 + a15) * 32 + g * 8];
#pragma unroll
    for (int mi = 0; mi < 4; ++mi)
#pragma unroll
      for (int ni = 0; ni < 4; ++ni)
        acc[mi][ni] = __builtin_amdgcn_mfma_f32_16x16x32_bf16(af[mi], bfr[ni], acc[mi][ni], 0, 0, 0);
    if (pf && qpart) {
      *(bf16x8*)&As[nxt][row0 * 32 + col0] = cvt8(x0, x1);
      *(bf16x8*)&As[nxt][(row0 + 64) * 32 + col0] = cvt8(y0, y1);
    }
    __syncthreads();
  }

  const int crow = blockIdx.x * 128 + wr * 64 + g * 4;
  const int ccol = yb * 128 + wc * 64 + a15;
  if (qpart) {
#pragma unroll
    for (int mi = 0; mi < 4; ++mi)
#pragma unroll
      for (int ni = 0; ni < 4; ++ni)
#pragma unroll
        for (int r = 0; r < 4; ++r)
          Qb[(crow + mi * 16 + r) * 1024 + ccol + ni * 16] = f2b(acc[mi][ni][r]);
  } else if (yb < 8) {
#pragma unroll
    for (int mi = 0; mi < 4; ++mi)
#pragma unroll
      for (int ni = 0; ni < 4; ++ni)
#pragma unroll
        for (int r = 0; r < 4; ++r)
          Kb[(crow + mi * 16 + r) * 1024 + ccol + ni * 16] = f2b(acc[mi][ni][r]);
  } else {
    // V part: Vt[((b*16+h)*64 + dd)*2048 + n], col c = ccol - 1024
#pragma unroll
    for (int mi = 0; mi < 4; ++mi) {
      const int n = crow + mi * 16;
      const int bq = n >> 11;
      const int nl = n & 2047;
#pragma unroll
      for (int ni = 0; ni < 4; ++ni) {
        const int c = ccol + ni * 16 - 1024;
        s16x4 v4;
        v4[0] = (short)f2b(acc[mi][ni][0]);
        v4[1] = (short)f2b(acc[mi][ni][1]);
        v4[2] = (short)f2b(acc[mi][ni][2]);
        v4[3] = (short)f2b(acc[mi][ni][3]);
        *(s16x4*)&Vtb[(((bq << 4) + (c >> 6)) * 64 + (c & 63)) * 2048 + nl] = v4;
      }
    }
  }
}

// ---------------- out-GEMM: C(f32) = A(bf16) * Bt^T, same 128^2 dbuf core ----------------
__global__ __launch_bounds__(256) void gemm_out(const u16* __restrict__ A,
                                                const u16* __restrict__ Bt,
                                                float* __restrict__ C) {
  __shared__ u16 As[2][128 * 32];
  __shared__ u16 Bs[2][128 * 32];
  const int t = threadIdx.x;
  const int wave = t >> 6, lane = t & 63;
  const int g = lane >> 4, a15 = lane & 15;
  const int wr = wave >> 1, wc = wave & 1;
  const int row0 = t >> 2;
  const int col0 = (t & 3) * 8;
  const int abase = (blockIdx.x * 128 + row0) * 1024 + col0;
  const int bbase = (blockIdx.y * 128 + row0) * 1024 + col0;

  f32x4 acc[4][4] = {};

  GLDS(A + abase, &As[0][wave * 512]);
  GLDS(A + abase + 64 * 1024, &As[0][2048 + wave * 512]);
  GLDS(Bt + bbase, &Bs[0][wave * 512]);
  GLDS(Bt + bbase + 64 * 1024, &Bs[0][2048 + wave * 512]);
  __syncthreads();

  for (int ki = 0; ki < 32; ++ki) {
    const int cur = ki & 1, nxt = cur ^ 1;
    const int ktn = (ki + 1) * 32;
    if (ki < 31) {
      GLDS(A + abase + ktn, &As[nxt][wave * 512]);
      GLDS(A + abase + 64 * 1024 + ktn, &As[nxt][2048 + wave * 512]);
      GLDS(Bt + bbase + ktn, &Bs[nxt][wave * 512]);
      GLDS(Bt + bbase + 64 * 1024 + ktn, &Bs[nxt][2048 + wave * 512]);
    }
    bf16x8 af[4], bfr[4];
#pragma unroll
    for (int mi = 0; mi < 4; ++mi)
      af[mi] = *(const bf16x8*)&As[cur][(wr * 64 + mi * 16 + a15) * 32 + g * 8];
#pragma unroll
    for (int ni = 0; ni < 4; ++ni)
      bfr[ni] = *(const bf16x8*)&Bs[cur][(wc * 64 + ni * 16 + a15) * 32 + g * 8];
#pragma unroll
    for (int mi = 0; mi < 4; ++mi)
#pragma unroll
      for (int ni = 0; ni < 4; ++ni)
        acc[mi][ni] = __builtin_amdgcn_mfma_f32_16x16x32_bf16(af[mi], bfr[ni], acc[mi][ni], 0, 0, 0);
    __syncthreads();
  }

  const int crow = blockIdx.x * 128 + wr * 64 + g * 4;
  const int ccol = blockIdx.y * 128 + wc * 64 + a15;
#pragma unroll
  for (int mi = 0; mi < 4; ++mi)
#pragma unroll
    for (int ni = 0; ni < 4; ++ni)
#pragma unroll
      for (int r = 0; r < 4; ++r)
        C[(crow + mi * 16 + r) * 1024 + ccol + ni * 16] = acc[mi][ni][r];
}

// ---------------- flash attention (r13-passing version, unchanged) ----------------
// 512-thread blocks (8 waves) sharing one K/V tile; grid 512 = 2 blocks/CU
// (16 waves/CU). Fixed-shift log2-domain softmax (exact by shift-invariance;
// EPS terms <=1e-8). O aliases Q (disjoint per-wave read/write regions).
__global__ __launch_bounds__(512) void attn_kernel(
    const u16* Q, const u16* __restrict__ K,
    const u16* __restrict__ Vt, const float* __restrict__ dec,
    u16* O) {
  const int f = blockIdx.x;
  const int bh = (f & 7) * 8 + ((f >> 3) & 7);   // 8 heads per XCD
  const int qx = f >> 6;                          // [0,8) q-tile of 256 rows
  const int b = bh >> 4, h = bh & 15;
  __shared__ u16 K_lds[2][64 * 64];
  __shared__ u16 V_lds[2][64 * 64];
  __shared__ __align__(16) u16 P_lds[8][32 * 72];
  __shared__ float l2p_lds[2048];

  const int wave = threadIdx.x >> 6, lane = threadIdx.x & 63;
  const int g = lane >> 4, a15 = lane & 15;
  u16* pl = &P_lds[wave][0];

  {
    const int i0 = threadIdx.x * 4;
    const float4 d0 = *(const float4*)&dec[b * 2048 + i0];
    float4 o0;
    o0.x = __log2f(fmaxf(1.f - d0.x, 1e-38f));
    o0.y = __log2f(fmaxf(1.f - d0.y, 1e-38f));
    o0.z = __log2f(fmaxf(1.f - d0.z, 1e-38f));
    o0.w = __log2f(fmaxf(1.f - d0.w, 1e-38f));
    *(float4*)&l2p_lds[i0] = o0;
  }

  bf16x8 qf[2][2];
  {
    const int qr = (b * 2048 + qx * 256 + wave * 32 + a15) * 1024 + h * 64 + g * 8;
#pragma unroll
    for (int qg = 0; qg < 2; ++qg) {
      qf[qg][0] = *(const bf16x8*)&Q[qr + qg * 16 * 1024];
      qf[qg][1] = *(const bf16x8*)&Q[qr + qg * 16 * 1024 + 32];
    }
  }

  const int srow = lane >> 3;
  const int swze = (((lane & 7) * 16) ^ (srow << 4)) >> 1;  // u16 elems
  const u16* Kg = K + ((size_t)(b * 2048 + wave * 8 + srow)) * 1024 + h * 64 + swze;
  const u16* Vg = Vt + ((size_t)(bh * 64 + wave * 8 + srow)) * 2048 + swze;
  u16* kdst[2] = {&K_lds[0][wave * 8 * 64], &K_lds[1][wave * 8 * 64]};
  u16* vdst[2] = {&V_lds[0][wave * 8 * 64], &V_lds[1][wave * 8 * 64]};

  GLDS(Kg, kdst[0]);
  GLDS(Vg, vdst[0]);
  __syncthreads();

  const float CSC = 0.125f * 1.44269504f;  // scale * log2(e)
  f32x4 acc[2][4] = {};
  f32x4 ls[2] = {};

  for (int it = 0; it < 32; ++it) {
    const int cur = it & 1, nxt = cur ^ 1;
    if (it < 31) {
      const int ktn = (it + 1) * 64;
      GLDS(Kg + (size_t)ktn * 1024, kdst[nxt]);
      GLDS(Vg + ktn, vdst[nxt]);
    }
    const int kt = it * 64;
    f32x4 sf[2][4];
#pragma unroll
    for (int sub = 0; sub < 4; ++sub) {
      const int krow = sub * 16 + a15;
      const char* kp = (const char*)&K_lds[cur][krow * 64];
      const int swz = (krow & 7) << 4;
      const bf16x8 k0 = *(const bf16x8*)(kp + ((g * 16) ^ swz));
      const bf16x8 k1 = *(const bf16x8*)(kp + ((g * 16 + 64) ^ swz));
#pragma unroll
      for (int qg = 0; qg < 2; ++qg) {
        f32x4 s = {0.f, 0.f, 0.f, 0.f};
        s = __builtin_amdgcn_mfma_f32_16x16x32_bf16(k0, qf[qg][0], s, 0, 0, 0);
        s = __builtin_amdgcn_mfma_f32_16x16x32_bf16(k1, qf[qg][1], s, 0, 0, 0);
        sf[qg][sub] = s;
      }
    }
#pragma unroll
    for (int qg = 0; qg < 2; ++qg) {
#pragma unroll
      for (int sub = 0; sub < 4; ++sub) {
        const float4 lp = *(const float4*)&l2p_lds[kt + sub * 16 + g * 4];
        const float e0 = __builtin_amdgcn_exp2f(fmaf(sf[qg][sub][0], CSC, lp.x));
        const float e1 = __builtin_amdgcn_exp2f(fmaf(sf[qg][sub][1], CSC, lp.y));
        const float e2 = __builtin_amdgcn_exp2f(fmaf(sf[qg][sub][2], CSC, lp.z));
        const float e3 = __builtin_amdgcn_exp2f(fmaf(sf[qg][sub][3], CSC, lp.w));
        ls[qg][0] += e0; ls[qg][1] += e1; ls[qg][2] += e2; ls[qg][3] += e3;
        unsigned int w0, w1;
        asm("v_cvt_pk_bf16_f32 %0, %1, %2" : "=v"(w0) : "v"(e0), "v"(e1));
        asm("v_cvt_pk_bf16_f32 %0, %1, %2" : "=v"(w1) : "v"(e2), "v"(e3));
        uint2 w; w.x = w0; w.y = w1;
        *(uint2*)&pl[(qg * 16 + a15) * 72 + sub * 16 + g * 4] = w;
      }
    }
    asm volatile("" ::: "memory");
#pragma unroll
    for (int kc = 0; kc < 2; ++kc) {
      const bf16x8 pa0 = *(const bf16x8*)&pl[a15 * 72 + kc * 32 + g * 8];
      const bf16x8 pa1 = *(const bf16x8*)&pl[(16 + a15) * 72 + kc * 32 + g * 8];
#pragma unroll
      for (int ni = 0; ni < 4; ++ni) {
        const int vrow = ni * 16 + a15;
        const char* vp = (const char*)&V_lds[cur][vrow * 64];
        const int vswz = (vrow & 7) << 4;
        const bf16x8 vb = *(const bf16x8*)(vp + ((kc * 64 + g * 16) ^ vswz));
        acc[0][ni] = __builtin_amdgcn_mfma_f32_16x16x32_bf16(pa0, vb, acc[0][ni], 0, 0, 0);
        acc[1][ni] = __builtin_amdgcn_mfma_f32_16x16x32_bf16(pa1, vb, acc[1][ni], 0, 0, 0);
      }
    }
    __syncthreads();
  }
#pragma unroll
  for (int qg = 0; qg < 2; ++qg) {
    float lsum = (ls[qg][0] + ls[qg][1]) + (ls[qg][2] + ls[qg][3]);
    lsum += __shfl_xor(lsum, 16);
    lsum += __shfl_xor(lsum, 32);
    const float li0 = 1.f / (__shfl(lsum, g * 4 + 0) + 1e-30f);
    const float li1 = 1.f / (__shfl(lsum, g * 4 + 1) + 1e-30f);
    const float li2 = 1.f / (__shfl(lsum, g * 4 + 2) + 1e-30f);
    const float li3 = 1.f / (__shfl(lsum, g * 4 + 3) + 1e-30f);
    const int obase = (b * 2048 + qx * 256 + wave * 32 + qg * 16 + g * 4) * 1024 + h * 64 + a15;
#pragma unroll
    for (int ni = 0; ni < 4; ++ni) {
      O[obase + 0 * 1024 + ni * 16] = f2b(acc[qg][ni][0] * li0);
      O[obase + 1 * 1024 + ni * 16] = f2b(acc[qg][ni][1] * li1);
      O[obase + 2 * 1024 + ni * 16] = f2b(acc[qg][ni][2] * li2);
      O[obase + 3 * 1024 + ni * 16] = f2b(acc[qg][ni][3] * li3);
    }
  }
}

extern "C" void kernel_launch(void* const* d_in, const int* in_sizes, int n_in,
                              void* d_out, int out_size, void* d_ws, size_t ws_size,
                              hipStream_t stream) {
  (void)in_sizes; (void)n_in; (void)out_size; (void)ws_size;
  const float* x   = (const float*)d_in[0];
  const float* xo  = (const float*)d_in[1];
  const float* dec = (const float*)d_in[2];
  const float* Wq  = (const float*)d_in[3];
  const float* Wk  = (const float*)d_in[4];
  const float* Wv  = (const float*)d_in[5];
  const float* Wp  = (const float*)d_in[6];
  float* out = (float*)d_out;

  // ws (40 MB): Wqt@0(2M) | Wkvt@2M(4M) | Wpt@6M(2M) | Qb@8M(16M, becomes O) |
  //   Vtb@24M(16M).
  // d_out (32 MiB) scratch before final overwrite: Kb@0 (16MiB bf16 K),
  // Xb@16MiB (16MiB bf16 xo).
  char* ws = (char*)d_ws;
  u16* Wqt  = (u16*)(ws + ((size_t)0 << 20));
  u16* Wkvt = (u16*)(ws + ((size_t)2 << 20));
  u16* Wpt  = (u16*)(ws + ((size_t)6 << 20));
  u16* Qb   = (u16*)(ws + ((size_t)8 << 20));
  u16* Vtb  = (u16*)(ws + ((size_t)24 << 20));
  u16* Kb   = (u16*)d_out;
  u16* Xb   = (u16*)((char*)d_out + ((size_t)16 << 20));

  const dim3 blk(256);
  transpose_w4<<<dim3(32, 32, 4), blk, 0, stream>>>(
      Wq, Wk, Wv, Wp, Wqt, Wkvt, Wkvt + 1024 * 1024, Wpt);

  cvt_f32_bf16<<<dim3(4096), blk, 0, stream>>>(xo, Xb);

  gemm_fused<<<dim3(64, 24), blk, 0, stream>>>(x, Xb, Wqt, Wkvt, Qb, Kb, Vtb);

  attn_kernel<<<dim3(512), dim3(512), 0, stream>>>(Qb, Kb, Vtb, dec, Qb);

  gemm_out<<<dim3(64, 8), blk, 0, stream>>>(Qb, Wpt, out);
}